// Round 6
// baseline (296.086 us; speedup 1.0000x reference)
//
#include <hip/hip_runtime.h>
#include <math.h>

#define B 2
#define T 4096
#define D 1024
#define DH 32
#define TNB 32        // 128-row tiles per batch
#define NBLK 528      // TNB*(TNB+1)/2 causal tile pairs
#define NK 12         // per-chunk candidates kept (safety margin over 8)
#define CPR (32*NK)   // candidates per row = 384

typedef __bf16 bf16x8 __attribute__((ext_vector_type(8)));
typedef float f32x4 __attribute__((ext_vector_type(4)));
typedef unsigned u32x4 __attribute__((ext_vector_type(4)));

#define AS1 __attribute__((address_space(1)))
#define AS3 __attribute__((address_space(3)))

// monotone f32 -> u32 (order-preserving); branchless
__device__ __forceinline__ unsigned mono32(float v) {
    unsigned u = __float_as_uint(v);
    u ^= ((unsigned)((int)u >> 31)) | 0x80000000u;
    return u;
}

// ---- wave-wide u32 max, result broadcast via readlane(63) (uniform/SGPR) ----
__device__ __forceinline__ unsigned dpp_umax_bcast(unsigned v) {
    #define DPPMAX(CTRL) { unsigned t_ = (unsigned)__builtin_amdgcn_update_dpp(0, (int)v, CTRL, 0xF, 0xF, true); v = v > t_ ? v : t_; }
    DPPMAX(0x111) DPPMAX(0x112) DPPMAX(0x114) DPPMAX(0x118)   // row_shr 1,2,4,8
    DPPMAX(0x142) DPPMAX(0x143)                               // row_bcast 15,31
    #undef DPPMAX
    return (unsigned)__builtin_amdgcn_readlane((int)v, 63);
}
// ---- wave-wide f32 sum, result broadcast via readlane(63) (uniform/SGPR) ----
__device__ __forceinline__ float dpp_fsum_bcast(float v) {
    #define DPPADD(CTRL) { int t_ = __builtin_amdgcn_update_dpp(0, __float_as_int(v), CTRL, 0xF, 0xF, true); v += __int_as_float(t_); }
    DPPADD(0x111) DPPADD(0x112) DPPADD(0x114) DPPADD(0x118)
    DPPADD(0x142) DPPADD(0x143)
    #undef DPPADD
    return __int_as_float(__builtin_amdgcn_readlane(__float_as_int(v), 63));
}
// ---- sum across each aligned 8-lane group (all lanes get the sum) ----
__device__ __forceinline__ float dpp_gsum8(float p) {
    { int t_ = __builtin_amdgcn_update_dpp(0, __float_as_int(p), 0x0B1, 0xF, 0xF, true); p += __int_as_float(t_); } // quad_perm xor1
    { int t_ = __builtin_amdgcn_update_dpp(0, __float_as_int(p), 0x04E, 0xF, 0xF, true); p += __int_as_float(t_); } // quad_perm xor2
    { int t_ = __builtin_amdgcn_update_dpp(0, __float_as_int(p), 0x141, 0xF, 0xF, true); p += __int_as_float(t_); } // row_half_mirror (xor7)
    return p;
}

// ---- bitonic merge of two sorted-desc 12-lists (packed unique keys) ----
__device__ __forceinline__ void merge12(const unsigned* a12, const unsigned* b12,
                                        unsigned* o12) {
    unsigned m16[16];
    #pragma unroll
    for (int i = 0; i < 16; ++i) {          // bitonic split, keep top-16
        unsigned aa = (i < NK) ? a12[i] : 0u;
        unsigned bb = (15 - i < NK) ? b12[15 - i] : 0u;
        m16[i] = aa > bb ? aa : bb;
    }
    #pragma unroll
    for (int g = 8; g >= 1; g >>= 1) {      // bitonic merge, descending
        #pragma unroll
        for (int i = 0; i < 16; ++i) {
            if (!(i & g)) {
                unsigned x0 = m16[i], x1 = m16[i + g];
                m16[i]     = x0 > x1 ? x0 : x1;
                m16[i + g] = x0 > x1 ? x1 : x0;
            }
        }
    }
    #pragma unroll
    for (int i = 0; i < NK; ++i) o12[i] = m16[i];
}

// ---------------- K_conv: src -> (hi, lo) bf16 split (2048 elems/block) -------
__global__ __launch_bounds__(256) void conv_kernel(const float* __restrict__ x,
        __bf16* __restrict__ xhi, __bf16* __restrict__ xlo)
{
    int i = (blockIdx.x * 256 + threadIdx.x) << 3;     // 8 floats/thread
    float4 a = *(const float4*)(x + i);
    float4 c = *(const float4*)(x + i + 4);
    float av[8] = {a.x, a.y, a.z, a.w, c.x, c.y, c.z, c.w};
    __bf16 h[8], l[8];
    #pragma unroll
    for (int j = 0; j < 8; ++j) {
        h[j] = (__bf16)av[j];
        l[j] = (__bf16)(av[j] - (float)h[j]);
    }
    *(float4*)(xhi + i) = *(float4*)h;
    *(float4*)(xlo + i) = *(float4*)l;
}

// ---------------- K0: per-batch column sums (for the t=0 row) ----------------
__global__ void mean_kernel(const float* __restrict__ x, float* __restrict__ meansum)
{
    int gid  = blockIdx.x;           // B * 4 dblk * 16 tch = 128 blocks
    int b    = gid >> 6;
    int rem  = gid & 63;
    int dblk = rem >> 4;
    int tch  = rem & 15;
    int d = dblk * 256 + threadIdx.x;
    const float* xp = x + (b * T + tch * 256) * D + d;
    float s = 0.f;
    #pragma unroll 8
    for (int it = 0; it < 256; ++it) s += xp[it * D];
    atomicAdd(&meansum[(b << 10) + d], s);
}

// ---------------- K1: q/k projection, split-bf16 MFMA, 64-row blocks ---------
__global__ __launch_bounds__(256) void qk_mfma_kernel(
        const __bf16* __restrict__ xhi, const __bf16* __restrict__ xlo,
        const __bf16* __restrict__ Whi, const __bf16* __restrict__ Wlo,
        float* __restrict__ qo, float* __restrict__ ko)
{
    __shared__ __align__(16) __bf16 stg[10240];
    __bf16* sAhi = stg;            // 64 x 40
    __bf16* sAlo = stg + 2560;
    __bf16* sBhi = stg + 5120;     // 64 x 40
    __bf16* sBlo = stg + 7680;

    int tid = threadIdx.x;
    int m0 = blockIdx.x << 6;
    int w = tid >> 6, lane = tid & 63;
    int fr = lane & 15, fq = lane >> 4;

    int arow = tid >> 2, aq = tid & 3;      // 4 chunks of 8 bf16 per row
    const __bf16* gAh = xhi + (size_t)(m0 + arow) * D + aq * 8;
    const __bf16* gAl = xlo + (size_t)(m0 + arow) * D + aq * 8;
    const __bf16* gBh = Whi + arow * D + aq * 8;
    const __bf16* gBl = Wlo + arow * D + aq * 8;

    f32x4 acc[4];
    #pragma unroll
    for (int j = 0; j < 4; ++j) acc[j] = (f32x4){0.f, 0.f, 0.f, 0.f};

    float4 a0 = *(const float4*)(gAh);
    float4 a1 = *(const float4*)(gAl);
    float4 b0 = *(const float4*)(gBh);
    float4 b1 = *(const float4*)(gBl);

    int sa = arow * 40 + aq * 8;

    for (int kc = 0; kc < 32; ++kc) {
        __syncthreads();
        *(float4*)(sAhi + sa) = a0;
        *(float4*)(sAlo + sa) = a1;
        *(float4*)(sBhi + sa) = b0;
        *(float4*)(sBlo + sa) = b1;
        __syncthreads();
        if (kc + 1 < 32) {
            int k0 = (kc + 1) << 5;
            a0 = *(const float4*)(gAh + k0);
            a1 = *(const float4*)(gAl + k0);
            b0 = *(const float4*)(gBh + k0);
            b1 = *(const float4*)(gBl + k0);
        }
        int r = (w << 4) + fr;
        bf16x8 fah = *(const bf16x8*)(sAhi + r * 40 + fq * 8);
        bf16x8 fal = *(const bf16x8*)(sAlo + r * 40 + fq * 8);
        bf16x8 fbh[4], fbl[4];
        #pragma unroll
        for (int j = 0; j < 4; ++j) {
            int rb = j * 16 + fr;
            fbh[j] = *(const bf16x8*)(sBhi + rb * 40 + fq * 8);
            fbl[j] = *(const bf16x8*)(sBlo + rb * 40 + fq * 8);
        }
        #pragma unroll
        for (int j = 0; j < 4; ++j) {
            acc[j] = __builtin_amdgcn_mfma_f32_16x16x32_bf16(fah, fbh[j], acc[j], 0, 0, 0);
            acc[j] = __builtin_amdgcn_mfma_f32_16x16x32_bf16(fah, fbl[j], acc[j], 0, 0, 0);
            acc[j] = __builtin_amdgcn_mfma_f32_16x16x32_bf16(fal, fbh[j], acc[j], 0, 0, 0);
        }
    }
    // writeout: C layout col=lane&15, row=fq*4+reg
    int grow0 = m0 + (w << 4) + (fq << 2);
    #pragma unroll
    for (int j = 0; j < 4; ++j) {
        int gn = j * 16 + fr;
        float* dst = (gn < 32) ? (qo + grow0 * DH + gn)
                               : (ko + grow0 * DH + gn - 32);
        dst[0]      = acc[j][0];
        dst[DH]     = acc[j][1];
        dst[2 * DH] = acc[j][2];
        dst[3 * DH] = acc[j][3];
    }
}

// ---------------- K2: hi-only bf16 MFMA sim GEMM + per-row top-12 per 128-col chunk
// A staged (3 buffers, 8KB each) via global_load_lds + counted vmcnt(6) +
// single barrier/iter; B fragments loaded DIRECTLY global->reg (64B-coalesced
// segments, compiler-tracked waits, 1-iter prefetch via unroll-2). LDS = Sbuf
// 33024 only -> 4 blocks/CU. Scan: in-wave; quarter-lane 32-col register
// scans (bank-rotated), 2x shfl_xor+bitonic merge12 levels, dwordx4 stores.
// Output: value[31:12] | (4095 - gidx).
__global__ __launch_bounds__(256, 4) void topk_mfma_kernel(
        const __bf16* __restrict__ xhi, unsigned* __restrict__ pkey)
{
    __shared__ __align__(16) char smem[33024];
    __bf16* stg = (__bf16*)smem;           // 3 A-bufs x 8192 B (rows 0-63 | 64-127)
    float* Sbuf = (float*)smem;            // 64 x 129 fp32 = 33024 B (post-loop)

    int tid = threadIdx.x;
    int b = blockIdx.x / NBLK;
    int l = blockIdx.x - b * NBLK;
    int rt = (int)((sqrtf(8.f * l + 1.f) - 1.f) * 0.5f);
    while ((rt + 1) * (rt + 2) / 2 <= l) ++rt;
    while (rt * (rt + 1) / 2 > l) --rt;
    int ct = l - rt * (rt + 1) / 2;
    int r0 = rt << 7, c0 = ct << 7;
    int base = b * T;

    int w = tid >> 6, lane = tid & 63;
    int wr = (w >> 1) << 6, wc = (w & 1) << 6;
    bool active = !(rt == ct && w == 1);   // diag block, fully non-causal quadrant
    int fr = lane & 15, fq = lane >> 4;    // fragment: row-in-tile, k-quad
    int fqs = (fq ^ ((fr >> 1) & 3)) << 3; // swizzled 16B-slot (bf16 offset), A only

    // A staging: lane i of wave w covers (row 16w + (i>>2), swizzled 16B-chunk)
    int lrow = lane >> 2;
    int lcq = (((lane & 3) ^ ((lane >> 3) & 3)) << 3);   // pre-swizzled source slot
    const __bf16* gA = xhi + (size_t)(base + r0) * D;
    const __bf16* gA0 = gA + (size_t)((w << 4) + lrow) * D + lcq;
    const __bf16* gA1 = gA0 + (size_t)64 * D;

    // B fragment bases: row bc = wc + i*16 + fr, 16B col-slot fq (no swizzle)
    const __bf16* gBf = xhi + (size_t)(base + c0) * D + fq * 8;
    size_t bOff[4];
    #pragma unroll
    for (int i = 0; i < 4; ++i) bOff[i] = (size_t)(wc + i * 16 + fr) * D;

    f32x4 acc[4][4];
    #pragma unroll
    for (int i = 0; i < 4; ++i)
        #pragma unroll
        for (int j = 0; j < 4; ++j) acc[i][j] = (f32x4){0.f, 0.f, 0.f, 0.f};

#define ISSUE_A(BUFBASE, KO) do { \
    __bf16* bA_ = (BUFBASE); \
    __builtin_amdgcn_global_load_lds((const AS1 unsigned int*)(gA0 + (KO)), \
        (AS3 unsigned int*)(bA_ + (w << 9)), 16, 0, 0); \
    __builtin_amdgcn_global_load_lds((const AS1 unsigned int*)(gA1 + (KO)), \
        (AS3 unsigned int*)(bA_ + 2048 + (w << 9)), 16, 0, 0); \
} while (0)

    bf16x8 bcur[4], bnxt[4];
    // prologue: A tiles 0,1 in flight; B(0) in regs
    ISSUE_A(stg, 0);
    ISSUE_A(stg + 4096, 32);
    #pragma unroll
    for (int i = 0; i < 4; ++i)
        bcur[i] = *(const bf16x8*)(gBf + bOff[i]);

    int bsel = 0, isel = 2;
    // steady outstanding at the wait: A(k+1)=2 + B(k)=4 -> vmcnt(6) drains A(k).
    // B loads are UNCONDITIONAL so every wave (incl. inactive diag quadrant)
    // accumulates the same counter and the ordinal drain retires its A-DMAs.
#define K_STEP(KC, USE, PRE) do { \
    asm volatile("s_waitcnt vmcnt(6)" ::: "memory"); \
    __builtin_amdgcn_s_barrier(); \
    asm volatile("" ::: "memory"); \
    if ((KC) + 2 < 32) { \
        ISSUE_A(stg + isel * 4096, ((KC) + 2) << 5); \
        isel = (isel == 2) ? 0 : isel + 1; \
    } \
    if ((KC) + 1 < 32) { \
        _Pragma("unroll") \
        for (int i_ = 0; i_ < 4; ++i_) \
            PRE[i_] = *(const bf16x8*)(gBf + bOff[i_] + (size_t)(((KC) + 1) << 5)); \
    } \
    if (active) { \
        const __bf16* cA_ = stg + bsel * 4096; \
        bf16x8 ah_[4]; \
        _Pragma("unroll") \
        for (int i_ = 0; i_ < 4; ++i_) { \
            int ar_ = wr + i_ * 16 + fr; \
            ah_[i_] = *(const bf16x8*)(cA_ + ar_ * 32 + fqs); \
        } \
        _Pragma("unroll") \
        for (int i_ = 0; i_ < 4; ++i_) \
            _Pragma("unroll") \
            for (int j_ = 0; j_ < 4; ++j_) \
                acc[i_][j_] = __builtin_amdgcn_mfma_f32_16x16x32_bf16(ah_[i_], USE[j_], acc[i_][j_], 0, 0, 0); \
    } \
    bsel = (bsel == 2) ? 0 : bsel + 1; \
} while (0)

    for (int kc2 = 0; kc2 < 16; ++kc2) {
        int kc = kc2 << 1;
        K_STEP(kc,     bcur, bnxt);
        K_STEP(kc + 1, bnxt, bcur);
    }
#undef K_STEP
#undef ISSUE_A

    int cr = fq << 2, cc = fr;             // C layout: col=lane&15, row=fq*4+reg
    int q = lane >> 4;                     // scan quarter
    #pragma unroll
    for (int phase = 0; phase < 2; ++phase) {
        __syncthreads();                   // staging reads / prior phase done
        if ((w >> 1) == phase) {           // waves owning rows [phase*64, +64)
            #pragma unroll
            for (int i = 0; i < 4; ++i)
                #pragma unroll
                for (int j = 0; j < 4; ++j) {
                    float* sp = Sbuf + (i * 16 + cr) * 129 + wc + j * 16 + cc;
                    sp[0]       = acc[i][j][0];
                    sp[129]     = acc[i][j][1];
                    sp[2 * 129] = acc[i][j][2];
                    sp[3 * 129] = acc[i][j][3];
                }
        }
        __syncthreads();
        // in-wave scan: wave w owns Sbuf rows w*16 + (lane&15); quarter q
        {
            int sr = (w << 4) + (lane & 15);
            int gt = r0 + (phase << 6) + sr;
            int cmax = gt - c0;
            if (cmax > 128) cmax = 128;
            if (cmax < 0) cmax = 0;
            int h0 = q << 5;
            int hmax = cmax < (h0 + 32) ? cmax : (h0 + 32);
            unsigned key[NK];
            #pragma unroll
            for (int i = 0; i < NK; ++i) key[i] = 0u;
            const float* Srow = Sbuf + sr * 129;
            #pragma unroll
            for (int mb = 0; mb < 4; ++mb) {           // bank-rotated batches
                int cb = h0 + (((mb + q) & 3) << 3);
                float v[8];
                #pragma unroll
                for (int j = 0; j < 8; ++j) v[j] = Srow[cb + j];   // 8 in flight
                #pragma unroll
                for (int j = 0; j < 8; ++j) {
                    int c = cb + j;
                    unsigned u = mono32(v[j]);
                    unsigned tk = (c < hmax) ? ((u & 0xFFFFFF80u) | (unsigned)(127 - c)) : 0u;
                    #pragma unroll
                    for (int i = 0; i < NK; ++i) {      // branchless sorted insert
                        unsigned hi = key[i] > tk ? key[i] : tk;
                        unsigned lo = key[i] > tk ? tk : key[i];
                        key[i] = hi; tk = lo;
                    }
                }
            }
            // merge quarters: lanes ^16 then ^32 (top-12 sets order-independent)
            #pragma unroll
            for (int lvl = 0; lvl < 2; ++lvl) {
                int xm = 16 << lvl;
                unsigned o12[NK], m12[NK];
                #pragma unroll
                for (int i = 0; i < NK; ++i) o12[i] = __shfl_xor(key[i], xm);
                merge12(key, o12, m12);
                #pragma unroll
                for (int i = 0; i < NK; ++i) key[i] = m12[i];
            }
            // store: lanes q<3 each write 4 keys as one dwordx4
            if (q < 3) {
                u32x4 ov;
                #pragma unroll
                for (int j = 0; j < 4; ++j) {
                    unsigned k0 = (q == 0) ? key[j] : (q == 1) ? key[4 + j] : key[8 + j];
                    // repack: value20 | (4095 - gcol), gcol = c0 + 127 - (k0&127)
                    ov[j] = k0 ? ((k0 & 0xFFFFF000u) | ((k0 & 127u) + (unsigned)(3968 - c0))) : 0u;
                }
                *(u32x4*)(pkey + (size_t)(base + gt) * CPR + ct * NK + (q << 2)) = ov;
            }
        }
    }
}

// ---------------- K3: FUSED wave-per-row selection + message + gelu ----------
// u32 packed-key candidates; 12 DPP extract-max passes (winners wave-uniform
// in SGPRs); scalar-addressed exact re-rank with DPP sum reduce; u64 exact
// top-8 insert; DPP 8-group score reduce. No LDS, no scratch, no bpermute.
__global__ __launch_bounds__(256) void select_msg_kernel(const float* __restrict__ x,
        const float* __restrict__ q, const float* __restrict__ k,
        const float* __restrict__ meansum,
        const unsigned* __restrict__ pkey,
        const float* __restrict__ gain, const float* __restrict__ bias,
        const float* __restrict__ plm, const float* __restrict__ pls,
        float* __restrict__ out)
{
    int tid = threadIdx.x;
    int w = tid >> 6, lane = tid & 63;
    int rid = (blockIdx.x << 2) + w;         // global row b*T+t
    int b = rid >> 12, t = rid & (T - 1);
    int ncand = NK * ((t + 127) >> 7);

    // candidate loads (all in flight)
    unsigned cv[6];
    #pragma unroll
    for (int u = 0; u < 6; ++u) {
        int cid = lane + (u << 6);
        cv[u] = (cid < ncand) ? pkey[(size_t)rid * CPR + cid] : 0u;
    }
    // prefetch xt fragments (independent of merge)
    const float* xt = x + (size_t)rid * D;
    float4 xt4[4];
    #pragma unroll
    for (int c = 0; c < 4; ++c)
        xt4[c] = *(const float4*)(xt + (c << 8) + (lane << 2));

    // 12 DPP extract-max passes -> wave-uniform winners (keys unique: idx in key)
    unsigned skey[NK]; int sgid[NK];
    #pragma unroll
    for (int i = 0; i < NK; ++i) {
        unsigned m = cv[0];
        #pragma unroll
        for (int u = 1; u < 6; ++u) m = m > cv[u] ? m : cv[u];
        m = dpp_umax_bcast(m);               // uniform (SGPR)
        skey[i] = m;
        sgid[i] = 4095 - (int)(m & 4095u);
        #pragma unroll
        for (int u = 0; u < 6; ++u) cv[u] = (cv[u] == m) ? 0u : cv[u];
    }

    // exact fp32 re-rank: 3 batches of 4; uniform row bases, DPP sum reduce
    float ex[NK];
    #pragma unroll
    for (int batch = 0; batch < 3; ++batch) {
        float4 rv[4][4];
        #pragma unroll
        for (int s = 0; s < 4; ++s) {
            int i = batch * 4 + s;
            int row = (skey[i] != 0u) ? sgid[i] : 0;
            const float* xj = x + (size_t)((b << 12) + row) * D;
            #pragma unroll
            for (int c = 0; c < 4; ++c)
                rv[s][c] = *(const float4*)(xj + (c << 8) + (lane << 2));
        }
        #pragma unroll
        for (int s = 0; s < 4; ++s) {
            float ss = 0.f;
            #pragma unroll
            for (int c = 0; c < 4; ++c)
                ss += xt4[c].x * rv[s][c].x + xt4[c].y * rv[s][c].y
                    + xt4[c].z * rv[s][c].z + xt4[c].w * rv[s][c].w;
            ex[batch * 4 + s] = dpp_fsum_bcast(ss);   // uniform
        }
    }

    // exact top-8 via u64 packed keys: (mono(value) << 12) | (4095 - idx)
    unsigned long long top8[8];
    #pragma unroll
    for (int r = 0; r < 8; ++r) top8[r] = 0ull;
    #pragma unroll
    for (int i = 0; i < NK; ++i) {
        unsigned u = mono32(ex[i]);
        unsigned long long t64 = (skey[i] != 0u)
            ? ((((unsigned long long)u) << 12) | (unsigned long long)(4095 - sgid[i]))
            : 0ull;
        #pragma unroll
        for (int r = 0; r < 8; ++r) {       // branchless sorted insert
            unsigned long long hi = (t64 > top8[r]) ? t64 : top8[r];
            unsigned long long lo = (t64 > top8[r]) ? top8[r] : t64;
            top8[r] = hi; t64 = lo;
        }
    }
    bool vld[8]; int bidx[8];
    #pragma unroll
    for (int i = 0; i < 8; ++i) {
        vld[i]  = top8[i] != 0ull;
        bidx[i] = 4095 - (int)(top8[i] & 4095ull);
    }

    // scores: lanes 8i..8i+7 compute dot(q[t], k[sel_i]); key via cndmask tree
    int i8 = lane >> 3, e = lane & 7;
    unsigned long long kk = (i8 & 4)
        ? ((i8 & 2) ? ((i8 & 1) ? top8[7] : top8[6]) : ((i8 & 1) ? top8[5] : top8[4]))
        : ((i8 & 2) ? ((i8 & 1) ? top8[3] : top8[2]) : ((i8 & 1) ? top8[1] : top8[0]));
    bool v8 = kk != 0ull;
    int g8 = v8 ? (4095 - (int)(kk & 4095ull)) : 0;
    float4 qv = *(const float4*)(q + (size_t)rid * DH + (e << 2));
    float4 kv = *(const float4*)(k + (size_t)((b << 12) + g8) * DH + (e << 2));
    float p = qv.x * kv.x + qv.y * kv.y + qv.z * kv.z + qv.w * kv.w;
    p = dpp_gsum8(p);
    p *= 0.17677669529663687f;               // 1/sqrt(32)

    float sc[8];
    #pragma unroll
    for (int i = 0; i < 8; ++i)
        sc[i] = __int_as_float(__builtin_amdgcn_readlane(__float_as_int(p), i << 3));

    float m = -INFINITY; int cnt = 0;
    #pragma unroll
    for (int i = 0; i < 8; ++i)
        if (vld[i]) { ++cnt; if (sc[i] > m) m = sc[i]; }

    float wgt[8]; float Z = 0.f; int gsel[8];
    #pragma unroll
    for (int i = 0; i < 8; ++i) {
        wgt[i] = vld[i] ? expf(sc[i] - m) : 0.f;
        Z += wgt[i];
        gsel[i] = vld[i] ? ((b << 12) + bidx[i]) : (b << 12);
    }
    float invZ = (cnt > 0) ? 1.f / Z : 0.f;
    #pragma unroll
    for (int i = 0; i < 8; ++i) wgt[i] *= invZ;

    // ---- fused epilogue: msg accumulation on lane's 16 dims + gelu ----
    float mix   = 1.f / (1.f + expf(-plm[0]));
    float scale = log1pf(expf(pls[0])) + 0.01f;
    const float onemix = 1.f - mix;

    float4 msg4[4];
    if (cnt == 0) {                          // t==0: uniform attention over ALL T
        #pragma unroll
        for (int c = 0; c < 4; ++c) {
            float4 ms = *(const float4*)(meansum + (b << 10) + (c << 8) + (lane << 2));
            msg4[c].x = ms.x * (1.f / (float)T); msg4[c].y = ms.y * (1.f / (float)T);
            msg4[c].z = ms.z * (1.f / (float)T); msg4[c].w = ms.w * (1.f / (float)T);
        }
    } else {
        #pragma unroll
        for (int c = 0; c < 4; ++c) msg4[c] = (float4){0.f, 0.f, 0.f, 0.f};
        #pragma unroll
        for (int g = 0; g < 2; ++g) {        // 2 batches of 4 rows (L2-hot re-read)
            float4 rv[4][4];
            #pragma unroll
            for (int s = 0; s < 4; ++s) {
                const float* xj = x + (size_t)gsel[g * 4 + s] * D;
                #pragma unroll
                for (int c = 0; c < 4; ++c)
                    rv[s][c] = *(const float4*)(xj + (c << 8) + (lane << 2));
            }
            #pragma unroll
            for (int s = 0; s < 4; ++s) {    // preserves i=0..7 summation order
                float wi = wgt[g * 4 + s];
                #pragma unroll
                for (int c = 0; c < 4; ++c) {
                    msg4[c].x += wi * rv[s][c].x; msg4[c].y += wi * rv[s][c].y;
                    msg4[c].z += wi * rv[s][c].z; msg4[c].w += wi * rv[s][c].w;
                }
            }
        }
    }
    #pragma unroll
    for (int c = 0; c < 4; ++c) {
        int d0 = (c << 8) + (lane << 2);
        float4 g4 = *(const float4*)(gain + d0);
        float4 b4 = *(const float4*)(bias + d0);
        float4 xv = xt4[c];
        float zi[4] = {
            (mix * xv.x + onemix * msg4[c].x) * g4.x + b4.x,
            (mix * xv.y + onemix * msg4[c].y) * g4.y + b4.y,
            (mix * xv.z + onemix * msg4[c].z) * g4.z + b4.z,
            (mix * xv.w + onemix * msg4[c].w) * g4.w + b4.w };
        float4 o4;
        o4.x = 0.5f * zi[0] * (1.f + erff(zi[0] * 0.70710678118654752f)) * scale;
        o4.y = 0.5f * zi[1] * (1.f + erff(zi[1] * 0.70710678118654752f)) * scale;
        o4.z = 0.5f * zi[2] * (1.f + erff(zi[2] * 0.70710678118654752f)) * scale;
        o4.w = 0.5f * zi[3] * (1.f + erff(zi[3] * 0.70710678118654752f)) * scale;
        *(float4*)(out + (size_t)rid * D + d0) = o4;
    }
}

extern "C" void kernel_launch(void* const* d_in, const int* in_sizes, int n_in,
                              void* d_out, int out_size, void* d_ws, size_t ws_size,
                              hipStream_t stream)
{
    const float* x    = (const float*)d_in[0];
    const float* Wq   = (const float*)d_in[1];
    const float* Wk   = (const float*)d_in[2];
    const float* gain = (const float*)d_in[3];
    const float* bias = (const float*)d_in[4];
    const float* plm  = (const float*)d_in[5];
    const float* pls  = (const float*)d_in[6];
    float* out = (float*)d_out;

    float* ws      = (float*)d_ws;
    float* q       = ws;                       // 262144
    float* k       = ws + 262144;              // 262144
    float* meansum = ws + 524288;              // 2048
    unsigned* pkey = (unsigned*)(ws + 526336); // B*T*CPR u32 = 3145728 slots
    __bf16* xhi    = (__bf16*)(ws + 3672064);  // B*T*D bf16 (4194304 float-slots)
    __bf16* xlo    = xhi + (size_t)B * T * D;
    __bf16* Whi    = xlo + (size_t)B * T * D;  // 64*1024 bf16
    __bf16* Wlo    = Whi + 64 * D;
    // total ws use: ~49 MB

    hipMemsetAsync(meansum, 0, 2048 * sizeof(float), stream);
    conv_kernel<<<B * T * D / 2048, 256, 0, stream>>>(x, xhi, xlo);
    conv_kernel<<<16, 256, 0, stream>>>(Wq, Whi, Wlo);
    conv_kernel<<<16, 256, 0, stream>>>(Wk, Whi + 32 * D, Wlo + 32 * D);
    mean_kernel<<<128, 256, 0, stream>>>(x, meansum);
    qk_mfma_kernel<<<B * T / 64, 256, 0, stream>>>(xhi, xlo, Whi, Wlo, q, k);
    topk_mfma_kernel<<<B * NBLK, 256, 0, stream>>>(xhi, pkey);
    select_msg_kernel<<<B * T / 4, 256, 0, stream>>>(x, q, k, meansum, pkey,
                                                     gain, bias, plm, pls, out);
}

// Round 7
// 262.572 us; speedup vs baseline: 1.1276x; 1.1276x over previous
//
#include <hip/hip_runtime.h>
#include <math.h>

#define B 2
#define T 4096
#define D 1024
#define DH 32
#define TNB 32        // 128-row tiles per batch
#define NBLK 528      // TNB*(TNB+1)/2 causal tile pairs
#define NK 12         // per-chunk candidates kept (safety margin over 8)
#define CPR (32*NK)   // candidates per row = 384

typedef __bf16 bf16x8 __attribute__((ext_vector_type(8)));
typedef float f32x4 __attribute__((ext_vector_type(4)));
typedef unsigned u32x4 __attribute__((ext_vector_type(4)));

#define AS1 __attribute__((address_space(1)))
#define AS3 __attribute__((address_space(3)))

// monotone f32 -> u32 (order-preserving); branchless
__device__ __forceinline__ unsigned mono32(float v) {
    unsigned u = __float_as_uint(v);
    u ^= ((unsigned)((int)u >> 31)) | 0x80000000u;
    return u;
}

// ---- wave-wide u32 max, result broadcast via readlane(63) (uniform/SGPR) ----
__device__ __forceinline__ unsigned dpp_umax_bcast(unsigned v) {
    #define DPPMAX(CTRL) { unsigned t_ = (unsigned)__builtin_amdgcn_update_dpp(0, (int)v, CTRL, 0xF, 0xF, true); v = v > t_ ? v : t_; }
    DPPMAX(0x111) DPPMAX(0x112) DPPMAX(0x114) DPPMAX(0x118)   // row_shr 1,2,4,8
    DPPMAX(0x142) DPPMAX(0x143)                               // row_bcast 15,31
    #undef DPPMAX
    return (unsigned)__builtin_amdgcn_readlane((int)v, 63);
}
// ---- wave-wide f32 sum, result broadcast via readlane(63) (uniform/SGPR) ----
__device__ __forceinline__ float dpp_fsum_bcast(float v) {
    #define DPPADD(CTRL) { int t_ = __builtin_amdgcn_update_dpp(0, __float_as_int(v), CTRL, 0xF, 0xF, true); v += __int_as_float(t_); }
    DPPADD(0x111) DPPADD(0x112) DPPADD(0x114) DPPADD(0x118)
    DPPADD(0x142) DPPADD(0x143)
    #undef DPPADD
    return __int_as_float(__builtin_amdgcn_readlane(__float_as_int(v), 63));
}
// ---- sum across each aligned 8-lane group (all lanes get the sum) ----
__device__ __forceinline__ float dpp_gsum8(float p) {
    { int t_ = __builtin_amdgcn_update_dpp(0, __float_as_int(p), 0x0B1, 0xF, 0xF, true); p += __int_as_float(t_); } // quad_perm xor1
    { int t_ = __builtin_amdgcn_update_dpp(0, __float_as_int(p), 0x04E, 0xF, 0xF, true); p += __int_as_float(t_); } // quad_perm xor2
    { int t_ = __builtin_amdgcn_update_dpp(0, __float_as_int(p), 0x141, 0xF, 0xF, true); p += __int_as_float(t_); } // row_half_mirror (xor7)
    return p;
}

// ---- bitonic merge of two sorted-desc 12-lists (packed unique keys) ----
__device__ __forceinline__ void merge12(const unsigned* a12, const unsigned* b12,
                                        unsigned* o12) {
    unsigned m16[16];
    #pragma unroll
    for (int i = 0; i < 16; ++i) {          // bitonic split, keep top-16
        unsigned aa = (i < NK) ? a12[i] : 0u;
        unsigned bb = (15 - i < NK) ? b12[15 - i] : 0u;
        m16[i] = aa > bb ? aa : bb;
    }
    #pragma unroll
    for (int g = 8; g >= 1; g >>= 1) {      // bitonic merge, descending
        #pragma unroll
        for (int i = 0; i < 16; ++i) {
            if (!(i & g)) {
                unsigned x0 = m16[i], x1 = m16[i + g];
                m16[i]     = x0 > x1 ? x0 : x1;
                m16[i + g] = x0 > x1 ? x1 : x0;
            }
        }
    }
    #pragma unroll
    for (int i = 0; i < NK; ++i) o12[i] = m16[i];
}

// ---------------- K_conv: src -> (hi, lo) bf16 split (2048 elems/block) -------
__global__ __launch_bounds__(256) void conv_kernel(const float* __restrict__ x,
        __bf16* __restrict__ xhi, __bf16* __restrict__ xlo)
{
    int i = (blockIdx.x * 256 + threadIdx.x) << 3;     // 8 floats/thread
    float4 a = *(const float4*)(x + i);
    float4 c = *(const float4*)(x + i + 4);
    float av[8] = {a.x, a.y, a.z, a.w, c.x, c.y, c.z, c.w};
    __bf16 h[8], l[8];
    #pragma unroll
    for (int j = 0; j < 8; ++j) {
        h[j] = (__bf16)av[j];
        l[j] = (__bf16)(av[j] - (float)h[j]);
    }
    *(float4*)(xhi + i) = *(float4*)h;
    *(float4*)(xlo + i) = *(float4*)l;
}

// ---------------- K0: per-batch column sums (for the t=0 row) ----------------
__global__ void mean_kernel(const float* __restrict__ x, float* __restrict__ meansum)
{
    int gid  = blockIdx.x;           // B * 4 dblk * 16 tch = 128 blocks
    int b    = gid >> 6;
    int rem  = gid & 63;
    int dblk = rem >> 4;
    int tch  = rem & 15;
    int d = dblk * 256 + threadIdx.x;
    const float* xp = x + (b * T + tch * 256) * D + d;
    float s = 0.f;
    #pragma unroll 8
    for (int it = 0; it < 256; ++it) s += xp[it * D];
    atomicAdd(&meansum[(b << 10) + d], s);
}

// ---------------- K1: q/k projection, split-bf16 MFMA, 64-row blocks ---------
__global__ __launch_bounds__(256) void qk_mfma_kernel(
        const __bf16* __restrict__ xhi, const __bf16* __restrict__ xlo,
        const __bf16* __restrict__ Whi, const __bf16* __restrict__ Wlo,
        float* __restrict__ qo, float* __restrict__ ko)
{
    __shared__ __align__(16) __bf16 stg[10240];
    __bf16* sAhi = stg;            // 64 x 40
    __bf16* sAlo = stg + 2560;
    __bf16* sBhi = stg + 5120;     // 64 x 40
    __bf16* sBlo = stg + 7680;

    int tid = threadIdx.x;
    int m0 = blockIdx.x << 6;
    int w = tid >> 6, lane = tid & 63;
    int fr = lane & 15, fq = lane >> 4;

    int arow = tid >> 2, aq = tid & 3;      // 4 chunks of 8 bf16 per row
    const __bf16* gAh = xhi + (size_t)(m0 + arow) * D + aq * 8;
    const __bf16* gAl = xlo + (size_t)(m0 + arow) * D + aq * 8;
    const __bf16* gBh = Whi + arow * D + aq * 8;
    const __bf16* gBl = Wlo + arow * D + aq * 8;

    f32x4 acc[4];
    #pragma unroll
    for (int j = 0; j < 4; ++j) acc[j] = (f32x4){0.f, 0.f, 0.f, 0.f};

    float4 a0 = *(const float4*)(gAh);
    float4 a1 = *(const float4*)(gAl);
    float4 b0 = *(const float4*)(gBh);
    float4 b1 = *(const float4*)(gBl);

    int sa = arow * 40 + aq * 8;

    for (int kc = 0; kc < 32; ++kc) {
        __syncthreads();
        *(float4*)(sAhi + sa) = a0;
        *(float4*)(sAlo + sa) = a1;
        *(float4*)(sBhi + sa) = b0;
        *(float4*)(sBlo + sa) = b1;
        __syncthreads();
        if (kc + 1 < 32) {
            int k0 = (kc + 1) << 5;
            a0 = *(const float4*)(gAh + k0);
            a1 = *(const float4*)(gAl + k0);
            b0 = *(const float4*)(gBh + k0);
            b1 = *(const float4*)(gBl + k0);
        }
        int r = (w << 4) + fr;
        bf16x8 fah = *(const bf16x8*)(sAhi + r * 40 + fq * 8);
        bf16x8 fal = *(const bf16x8*)(sAlo + r * 40 + fq * 8);
        bf16x8 fbh[4], fbl[4];
        #pragma unroll
        for (int j = 0; j < 4; ++j) {
            int rb = j * 16 + fr;
            fbh[j] = *(const bf16x8*)(sBhi + rb * 40 + fq * 8);
            fbl[j] = *(const bf16x8*)(sBlo + rb * 40 + fq * 8);
        }
        #pragma unroll
        for (int j = 0; j < 4; ++j) {
            acc[j] = __builtin_amdgcn_mfma_f32_16x16x32_bf16(fah, fbh[j], acc[j], 0, 0, 0);
            acc[j] = __builtin_amdgcn_mfma_f32_16x16x32_bf16(fah, fbl[j], acc[j], 0, 0, 0);
            acc[j] = __builtin_amdgcn_mfma_f32_16x16x32_bf16(fal, fbh[j], acc[j], 0, 0, 0);
        }
    }
    // writeout: C layout col=lane&15, row=fq*4+reg
    int grow0 = m0 + (w << 4) + (fq << 2);
    #pragma unroll
    for (int j = 0; j < 4; ++j) {
        int gn = j * 16 + fr;
        float* dst = (gn < 32) ? (qo + grow0 * DH + gn)
                               : (ko + grow0 * DH + gn - 32);
        dst[0]      = acc[j][0];
        dst[DH]     = acc[j][1];
        dst[2 * DH] = acc[j][2];
        dst[3 * DH] = acc[j][3];
    }
}

// ---------------- K2: hi-only bf16 MFMA sim GEMM + per-row top-12 per 128-col chunk
// Split-depth staging: A triple-buffered (3x8KB), B double-buffered (2x8KB)
// = 40960 B LDS -> 4 blocks/CU, with r4's single-barrier counted-vmcnt
// pipeline. Per iter: wait vmcnt(2) [drains A(k),B(k); A(k+1) stays in
// flight] -> barrier -> issue B(k+1), A(k+2) (buffers last read iter k-1:
// WAR-safe with one barrier) -> compute. Scan: in-wave; quarter-lane 32-col
// register scans (bank-rotated), 2x shfl_xor+merge12, dwordx4 stores.
// Output: value[31:12] | (4095 - gidx).
__global__ __launch_bounds__(256, 4) void topk_mfma_kernel(
        const __bf16* __restrict__ xhi, unsigned* __restrict__ pkey)
{
    __shared__ __align__(16) char smem[40960];
    __bf16* stg = (__bf16*)smem;   // A bufs @ 0,4096,8192; B bufs @ 12288,16384 (bf16 units)
    float* Sbuf = (float*)smem;    // 64 x 129 fp32 = 33024 B (post-loop)

    int tid = threadIdx.x;
    int b = blockIdx.x / NBLK;
    int l = blockIdx.x - b * NBLK;
    int rt = (int)((sqrtf(8.f * l + 1.f) - 1.f) * 0.5f);
    while ((rt + 1) * (rt + 2) / 2 <= l) ++rt;
    while (rt * (rt + 1) / 2 > l) --rt;
    int ct = l - rt * (rt + 1) / 2;
    int r0 = rt << 7, c0 = ct << 7;
    int base = b * T;

    int w = tid >> 6, lane = tid & 63;
    int wr = (w >> 1) << 6, wc = (w & 1) << 6;
    bool active = !(rt == ct && w == 1);   // diag block, fully non-causal quadrant
    int fr = lane & 15, fq = lane >> 4;    // fragment: row-in-tile, k-quad
    int fqs = (fq ^ ((fr >> 1) & 3)) << 3; // swizzled 16B-slot (bf16 offset)

    // staging: lane i of wave w covers (row 16w + (i>>2), swizzled 16B-chunk)
    int lrow = lane >> 2;
    int lcq = (((lane & 3) ^ ((lane >> 3) & 3)) << 3);   // pre-swizzled source slot
    const __bf16* gA = xhi + (size_t)(base + r0) * D;
    const __bf16* gB = xhi + (size_t)(base + c0) * D;
    const __bf16* gA0 = gA + (size_t)((w << 4) + lrow) * D + lcq;
    const __bf16* gA1 = gA0 + (size_t)64 * D;
    const __bf16* gB0 = gB + (size_t)((w << 4) + lrow) * D + lcq;
    const __bf16* gB1 = gB0 + (size_t)64 * D;

    f32x4 acc[4][4];
    #pragma unroll
    for (int i = 0; i < 4; ++i)
        #pragma unroll
        for (int j = 0; j < 4; ++j) acc[i][j] = (f32x4){0.f, 0.f, 0.f, 0.f};

#define ISSUE_A(BUFBASE, KO) do { \
    __bf16* bA_ = (BUFBASE); \
    __builtin_amdgcn_global_load_lds((const AS1 unsigned int*)(gA0 + (KO)), \
        (AS3 unsigned int*)(bA_ + (w << 9)), 16, 0, 0); \
    __builtin_amdgcn_global_load_lds((const AS1 unsigned int*)(gA1 + (KO)), \
        (AS3 unsigned int*)(bA_ + 2048 + (w << 9)), 16, 0, 0); \
} while (0)
#define ISSUE_B(BUFBASE, KO) do { \
    __bf16* bB_ = (BUFBASE); \
    __builtin_amdgcn_global_load_lds((const AS1 unsigned int*)(gB0 + (KO)), \
        (AS3 unsigned int*)(bB_ + (w << 9)), 16, 0, 0); \
    __builtin_amdgcn_global_load_lds((const AS1 unsigned int*)(gB1 + (KO)), \
        (AS3 unsigned int*)(bB_ + 2048 + (w << 9)), 16, 0, 0); \
} while (0)

    // prologue, ordinal [B(0), A(0), A(1)]
    ISSUE_B(stg + 12288, 0);
    ISSUE_A(stg, 0);
    ISSUE_A(stg + 4096, 32);

    int asel = 0, isel = 2;
    for (int kc = 0; kc < 32; ++kc) {
        // steady outstanding at wait: [A(k) 2, B(k) 2, A(k+1) 2] (oldest->newest)
        // vmcnt(2) drains A(k), B(k); A(k+1)'s 2 loads stay in flight.
        if (kc < 31) { asm volatile("s_waitcnt vmcnt(2)" ::: "memory"); }
        else         { asm volatile("s_waitcnt vmcnt(0)" ::: "memory"); }
        __builtin_amdgcn_s_barrier();      // buffers for tile kc visible
        asm volatile("" ::: "memory");
        if (kc + 1 < 32)                   // B(k+1) into bbuf[(k+1)&1] (read iter k-1)
            ISSUE_B(stg + 12288 + (((kc + 1) & 1) << 12), (kc + 1) << 5);
        if (kc + 2 < 32) {                 // A(k+2) into abuf[(k+2)%3] (read iter k-1)
            ISSUE_A(stg + (isel << 12), (kc + 2) << 5);
            isel = (isel == 2) ? 0 : isel + 1;
        }
        if (active) {
            const __bf16* cA = stg + (asel << 12);
            const __bf16* cB = stg + 12288 + ((kc & 1) << 12);
            bf16x8 ah[4], bh[4];
            #pragma unroll
            for (int i = 0; i < 4; ++i) {
                int ar = wr + i * 16 + fr;
                ah[i] = *(const bf16x8*)(cA + ar * 32 + fqs);
                int bc = wc + i * 16 + fr;
                bh[i] = *(const bf16x8*)(cB + bc * 32 + fqs);
            }
            #pragma unroll
            for (int i = 0; i < 4; ++i)
                #pragma unroll
                for (int j = 0; j < 4; ++j)
                    acc[i][j] = __builtin_amdgcn_mfma_f32_16x16x32_bf16(ah[i], bh[j], acc[i][j], 0, 0, 0);
        }
        asel = (asel == 2) ? 0 : asel + 1;
    }
#undef ISSUE_A
#undef ISSUE_B

    int cr = fq << 2, cc = fr;             // C layout: col=lane&15, row=fq*4+reg
    int q = lane >> 4;                     // scan quarter
    #pragma unroll
    for (int phase = 0; phase < 2; ++phase) {
        __syncthreads();                   // staging reads / prior phase done
        if ((w >> 1) == phase) {           // waves owning rows [phase*64, +64)
            #pragma unroll
            for (int i = 0; i < 4; ++i)
                #pragma unroll
                for (int j = 0; j < 4; ++j) {
                    float* sp = Sbuf + (i * 16 + cr) * 129 + wc + j * 16 + cc;
                    sp[0]       = acc[i][j][0];
                    sp[129]     = acc[i][j][1];
                    sp[2 * 129] = acc[i][j][2];
                    sp[3 * 129] = acc[i][j][3];
                }
        }
        __syncthreads();
        // in-wave scan: wave w owns Sbuf rows w*16 + (lane&15); quarter q
        {
            int sr = (w << 4) + (lane & 15);
            int gt = r0 + (phase << 6) + sr;
            int cmax = gt - c0;
            if (cmax > 128) cmax = 128;
            if (cmax < 0) cmax = 0;
            int h0 = q << 5;
            int hmax = cmax < (h0 + 32) ? cmax : (h0 + 32);
            unsigned key[NK];
            #pragma unroll
            for (int i = 0; i < NK; ++i) key[i] = 0u;
            const float* Srow = Sbuf + sr * 129;
            #pragma unroll
            for (int mb = 0; mb < 4; ++mb) {           // bank-rotated batches
                int cb = h0 + (((mb + q) & 3) << 3);
                float v[8];
                #pragma unroll
                for (int j = 0; j < 8; ++j) v[j] = Srow[cb + j];   // 8 in flight
                #pragma unroll
                for (int j = 0; j < 8; ++j) {
                    int c = cb + j;
                    unsigned u = mono32(v[j]);
                    unsigned tk = (c < hmax) ? ((u & 0xFFFFFF80u) | (unsigned)(127 - c)) : 0u;
                    #pragma unroll
                    for (int i = 0; i < NK; ++i) {      // branchless sorted insert
                        unsigned hi = key[i] > tk ? key[i] : tk;
                        unsigned lo = key[i] > tk ? tk : key[i];
                        key[i] = hi; tk = lo;
                    }
                }
            }
            // merge quarters: lanes ^16 then ^32 (top-12 sets order-independent)
            #pragma unroll
            for (int lvl = 0; lvl < 2; ++lvl) {
                int xm = 16 << lvl;
                unsigned o12[NK], m12[NK];
                #pragma unroll
                for (int i = 0; i < NK; ++i) o12[i] = __shfl_xor(key[i], xm);
                merge12(key, o12, m12);
                #pragma unroll
                for (int i = 0; i < NK; ++i) key[i] = m12[i];
            }
            // store: lanes q<3 each write 4 keys as one dwordx4
            if (q < 3) {
                u32x4 ov;
                #pragma unroll
                for (int j = 0; j < 4; ++j) {
                    unsigned k0 = (q == 0) ? key[j] : (q == 1) ? key[4 + j] : key[8 + j];
                    // repack: value20 | (4095 - gcol), gcol = c0 + 127 - (k0&127)
                    ov[j] = k0 ? ((k0 & 0xFFFFF000u) | ((k0 & 127u) + (unsigned)(3968 - c0))) : 0u;
                }
                *(u32x4*)(pkey + (size_t)(base + gt) * CPR + ct * NK + (q << 2)) = ov;
            }
        }
    }
}

// ---------------- K3: FUSED wave-per-row selection + message + gelu ----------
// u32 packed-key candidates; 12 DPP extract-max passes (winners wave-uniform
// in SGPRs); scalar-addressed exact re-rank with DPP sum reduce; u64 exact
// top-8 insert; DPP 8-group score reduce. No LDS, no scratch, no bpermute.
__global__ __launch_bounds__(256) void select_msg_kernel(const float* __restrict__ x,
        const float* __restrict__ q, const float* __restrict__ k,
        const float* __restrict__ meansum,
        const unsigned* __restrict__ pkey,
        const float* __restrict__ gain, const float* __restrict__ bias,
        const float* __restrict__ plm, const float* __restrict__ pls,
        float* __restrict__ out)
{
    int tid = threadIdx.x;
    int w = tid >> 6, lane = tid & 63;
    int rid = (blockIdx.x << 2) + w;         // global row b*T+t
    int b = rid >> 12, t = rid & (T - 1);
    int ncand = NK * ((t + 127) >> 7);

    // candidate loads (all in flight)
    unsigned cv[6];
    #pragma unroll
    for (int u = 0; u < 6; ++u) {
        int cid = lane + (u << 6);
        cv[u] = (cid < ncand) ? pkey[(size_t)rid * CPR + cid] : 0u;
    }
    // prefetch xt fragments (independent of merge)
    const float* xt = x + (size_t)rid * D;
    float4 xt4[4];
    #pragma unroll
    for (int c = 0; c < 4; ++c)
        xt4[c] = *(const float4*)(xt + (c << 8) + (lane << 2));

    // 12 DPP extract-max passes -> wave-uniform winners (keys unique: idx in key)
    unsigned skey[NK]; int sgid[NK];
    #pragma unroll
    for (int i = 0; i < NK; ++i) {
        unsigned m = cv[0];
        #pragma unroll
        for (int u = 1; u < 6; ++u) m = m > cv[u] ? m : cv[u];
        m = dpp_umax_bcast(m);               // uniform (SGPR)
        skey[i] = m;
        sgid[i] = 4095 - (int)(m & 4095u);
        #pragma unroll
        for (int u = 0; u < 6; ++u) cv[u] = (cv[u] == m) ? 0u : cv[u];
    }

    // exact fp32 re-rank: 3 batches of 4; uniform row bases, DPP sum reduce
    float ex[NK];
    #pragma unroll
    for (int batch = 0; batch < 3; ++batch) {
        float4 rv[4][4];
        #pragma unroll
        for (int s = 0; s < 4; ++s) {
            int i = batch * 4 + s;
            int row = (skey[i] != 0u) ? sgid[i] : 0;
            const float* xj = x + (size_t)((b << 12) + row) * D;
            #pragma unroll
            for (int c = 0; c < 4; ++c)
                rv[s][c] = *(const float4*)(xj + (c << 8) + (lane << 2));
        }
        #pragma unroll
        for (int s = 0; s < 4; ++s) {
            float ss = 0.f;
            #pragma unroll
            for (int c = 0; c < 4; ++c)
                ss += xt4[c].x * rv[s][c].x + xt4[c].y * rv[s][c].y
                    + xt4[c].z * rv[s][c].z + xt4[c].w * rv[s][c].w;
            ex[batch * 4 + s] = dpp_fsum_bcast(ss);   // uniform
        }
    }

    // exact top-8 via u64 packed keys: (mono(value) << 12) | (4095 - idx)
    unsigned long long top8[8];
    #pragma unroll
    for (int r = 0; r < 8; ++r) top8[r] = 0ull;
    #pragma unroll
    for (int i = 0; i < NK; ++i) {
        unsigned u = mono32(ex[i]);
        unsigned long long t64 = (skey[i] != 0u)
            ? ((((unsigned long long)u) << 12) | (unsigned long long)(4095 - sgid[i]))
            : 0ull;
        #pragma unroll
        for (int r = 0; r < 8; ++r) {       // branchless sorted insert
            unsigned long long hi = (t64 > top8[r]) ? t64 : top8[r];
            unsigned long long lo = (t64 > top8[r]) ? top8[r] : t64;
            top8[r] = hi; t64 = lo;
        }
    }
    bool vld[8]; int bidx[8];
    #pragma unroll
    for (int i = 0; i < 8; ++i) {
        vld[i]  = top8[i] != 0ull;
        bidx[i] = 4095 - (int)(top8[i] & 4095ull);
    }

    // scores: lanes 8i..8i+7 compute dot(q[t], k[sel_i]); key via cndmask tree
    int i8 = lane >> 3, e = lane & 7;
    unsigned long long kk = (i8 & 4)
        ? ((i8 & 2) ? ((i8 & 1) ? top8[7] : top8[6]) : ((i8 & 1) ? top8[5] : top8[4]))
        : ((i8 & 2) ? ((i8 & 1) ? top8[3] : top8[2]) : ((i8 & 1) ? top8[1] : top8[0]));
    bool v8 = kk != 0ull;
    int g8 = v8 ? (4095 - (int)(kk & 4095ull)) : 0;
    float4 qv = *(const float4*)(q + (size_t)rid * DH + (e << 2));
    float4 kv = *(const float4*)(k + (size_t)((b << 12) + g8) * DH + (e << 2));
    float p = qv.x * kv.x + qv.y * kv.y + qv.z * kv.z + qv.w * kv.w;
    p = dpp_gsum8(p);
    p *= 0.17677669529663687f;               // 1/sqrt(32)

    float sc[8];
    #pragma unroll
    for (int i = 0; i < 8; ++i)
        sc[i] = __int_as_float(__builtin_amdgcn_readlane(__float_as_int(p), i << 3));

    float m = -INFINITY; int cnt = 0;
    #pragma unroll
    for (int i = 0; i < 8; ++i)
        if (vld[i]) { ++cnt; if (sc[i] > m) m = sc[i]; }

    float wgt[8]; float Z = 0.f; int gsel[8];
    #pragma unroll
    for (int i = 0; i < 8; ++i) {
        wgt[i] = vld[i] ? expf(sc[i] - m) : 0.f;
        Z += wgt[i];
        gsel[i] = vld[i] ? ((b << 12) + bidx[i]) : (b << 12);
    }
    float invZ = (cnt > 0) ? 1.f / Z : 0.f;
    #pragma unroll
    for (int i = 0; i < 8; ++i) wgt[i] *= invZ;

    // ---- fused epilogue: msg accumulation on lane's 16 dims + gelu ----
    float mix   = 1.f / (1.f + expf(-plm[0]));
    float scale = log1pf(expf(pls[0])) + 0.01f;
    const float onemix = 1.f - mix;

    float4 msg4[4];
    if (cnt == 0) {                          // t==0: uniform attention over ALL T
        #pragma unroll
        for (int c = 0; c < 4; ++c) {
            float4 ms = *(const float4*)(meansum + (b << 10) + (c << 8) + (lane << 2));
            msg4[c].x = ms.x * (1.f / (float)T); msg4[c].y = ms.y * (1.f / (float)T);
            msg4[c].z = ms.z * (1.f / (float)T); msg4[c].w = ms.w * (1.f / (float)T);
        }
    } else {
        #pragma unroll
        for (int c = 0; c < 4; ++c) msg4[c] = (float4){0.f, 0.f, 0.f, 0.f};
        #pragma unroll
        for (int g = 0; g < 2; ++g) {        // 2 batches of 4 rows (L2-hot re-read)
            float4 rv[4][4];
            #pragma unroll
            for (int s = 0; s < 4; ++s) {
                const float* xj = x + (size_t)gsel[g * 4 + s] * D;
                #pragma unroll
                for (int c = 0; c < 4; ++c)
                    rv[s][c] = *(const float4*)(xj + (c << 8) + (lane << 2));
            }
            #pragma unroll
            for (int s = 0; s < 4; ++s) {    // preserves i=0..7 summation order
                float wi = wgt[g * 4 + s];
                #pragma unroll
                for (int c = 0; c < 4; ++c) {
                    msg4[c].x += wi * rv[s][c].x; msg4[c].y += wi * rv[s][c].y;
                    msg4[c].z += wi * rv[s][c].z; msg4[c].w += wi * rv[s][c].w;
                }
            }
        }
    }
    #pragma unroll
    for (int c = 0; c < 4; ++c) {
        int d0 = (c << 8) + (lane << 2);
        float4 g4 = *(const float4*)(gain + d0);
        float4 b4 = *(const float4*)(bias + d0);
        float4 xv = xt4[c];
        float zi[4] = {
            (mix * xv.x + onemix * msg4[c].x) * g4.x + b4.x,
            (mix * xv.y + onemix * msg4[c].y) * g4.y + b4.y,
            (mix * xv.z + onemix * msg4[c].z) * g4.z + b4.z,
            (mix * xv.w + onemix * msg4[c].w) * g4.w + b4.w };
        float4 o4;
        o4.x = 0.5f * zi[0] * (1.f + erff(zi[0] * 0.70710678118654752f)) * scale;
        o4.y = 0.5f * zi[1] * (1.f + erff(zi[1] * 0.70710678118654752f)) * scale;
        o4.z = 0.5f * zi[2] * (1.f + erff(zi[2] * 0.70710678118654752f)) * scale;
        o4.w = 0.5f * zi[3] * (1.f + erff(zi[3] * 0.70710678118654752f)) * scale;
        *(float4*)(out + (size_t)rid * D + d0) = o4;
    }
}

extern "C" void kernel_launch(void* const* d_in, const int* in_sizes, int n_in,
                              void* d_out, int out_size, void* d_ws, size_t ws_size,
                              hipStream_t stream)
{
    const float* x    = (const float*)d_in[0];
    const float* Wq   = (const float*)d_in[1];
    const float* Wk   = (const float*)d_in[2];
    const float* gain = (const float*)d_in[3];
    const float* bias = (const float*)d_in[4];
    const float* plm  = (const float*)d_in[5];
    const float* pls  = (const float*)d_in[6];
    float* out = (float*)d_out;

    float* ws      = (float*)d_ws;
    float* q       = ws;                       // 262144
    float* k       = ws + 262144;              // 262144
    float* meansum = ws + 524288;              // 2048
    unsigned* pkey = (unsigned*)(ws + 526336); // B*T*CPR u32 = 3145728 slots
    __bf16* xhi    = (__bf16*)(ws + 3672064);  // B*T*D bf16 (4194304 float-slots)
    __bf16* xlo    = xhi + (size_t)B * T * D;
    __bf16* Whi    = xlo + (size_t)B * T * D;  // 64*1024 bf16
    __bf16* Wlo    = Whi + 64 * D;
    // total ws use: ~49 MB

    hipMemsetAsync(meansum, 0, 2048 * sizeof(float), stream);
    conv_kernel<<<B * T * D / 2048, 256, 0, stream>>>(x, xhi, xlo);
    conv_kernel<<<16, 256, 0, stream>>>(Wq, Whi, Wlo);
    conv_kernel<<<16, 256, 0, stream>>>(Wk, Whi + 32 * D, Wlo + 32 * D);
    mean_kernel<<<128, 256, 0, stream>>>(x, meansum);
    qk_mfma_kernel<<<B * T / 64, 256, 0, stream>>>(xhi, xlo, Whi, Wlo, q, k);
    topk_mfma_kernel<<<B * NBLK, 256, 0, stream>>>(xhi, pkey);
    select_msg_kernel<<<B * T / 4, 256, 0, stream>>>(x, q, k, meansum, pkey,
                                                     gain, bias, plm, pls, out);
}

// Round 8
// 233.378 us; speedup vs baseline: 1.2687x; 1.1251x over previous
//
#include <hip/hip_runtime.h>
#include <math.h>

#define B 2
#define T 4096
#define D 1024
#define DH 32
#define TNB 32        // 128-row tiles per batch
#define NBLK 528      // TNB*(TNB+1)/2 causal tile pairs
#define NK 12         // per-chunk candidates kept (safety margin over 8)
#define CPR (32*NK)   // candidates per row = 384

typedef __bf16 bf16x8 __attribute__((ext_vector_type(8)));
typedef float f32x4 __attribute__((ext_vector_type(4)));
typedef unsigned u32x4 __attribute__((ext_vector_type(4)));

#define AS1 __attribute__((address_space(1)))
#define AS3 __attribute__((address_space(3)))

// monotone f32 -> u32 (order-preserving); branchless
__device__ __forceinline__ unsigned mono32(float v) {
    unsigned u = __float_as_uint(v);
    u ^= ((unsigned)((int)u >> 31)) | 0x80000000u;
    return u;
}

// ---- wave-wide u32 max, result broadcast via readlane(63) (uniform/SGPR) ----
__device__ __forceinline__ unsigned dpp_umax_bcast(unsigned v) {
    #define DPPMAX(CTRL) { unsigned t_ = (unsigned)__builtin_amdgcn_update_dpp(0, (int)v, CTRL, 0xF, 0xF, true); v = v > t_ ? v : t_; }
    DPPMAX(0x111) DPPMAX(0x112) DPPMAX(0x114) DPPMAX(0x118)   // row_shr 1,2,4,8
    DPPMAX(0x142) DPPMAX(0x143)                               // row_bcast 15,31
    #undef DPPMAX
    return (unsigned)__builtin_amdgcn_readlane((int)v, 63);
}
// ---- wave-wide f32 sum, result broadcast via readlane(63) (uniform/SGPR) ----
__device__ __forceinline__ float dpp_fsum_bcast(float v) {
    #define DPPADD(CTRL) { int t_ = __builtin_amdgcn_update_dpp(0, __float_as_int(v), CTRL, 0xF, 0xF, true); v += __int_as_float(t_); }
    DPPADD(0x111) DPPADD(0x112) DPPADD(0x114) DPPADD(0x118)
    DPPADD(0x142) DPPADD(0x143)
    #undef DPPADD
    return __int_as_float(__builtin_amdgcn_readlane(__float_as_int(v), 63));
}
// ---- sum across each aligned 8-lane group (all lanes get the sum) ----
__device__ __forceinline__ float dpp_gsum8(float p) {
    { int t_ = __builtin_amdgcn_update_dpp(0, __float_as_int(p), 0x0B1, 0xF, 0xF, true); p += __int_as_float(t_); } // quad_perm xor1
    { int t_ = __builtin_amdgcn_update_dpp(0, __float_as_int(p), 0x04E, 0xF, 0xF, true); p += __int_as_float(t_); } // quad_perm xor2
    { int t_ = __builtin_amdgcn_update_dpp(0, __float_as_int(p), 0x141, 0xF, 0xF, true); p += __int_as_float(t_); } // row_half_mirror (xor7)
    return p;
}

// ---- bitonic merge of two sorted-desc 12-lists (packed unique keys) ----
__device__ __forceinline__ void merge12(const unsigned* a12, const unsigned* b12,
                                        unsigned* o12) {
    unsigned m16[16];
    #pragma unroll
    for (int i = 0; i < 16; ++i) {          // bitonic split, keep top-16
        unsigned aa = (i < NK) ? a12[i] : 0u;
        unsigned bb = (15 - i < NK) ? b12[15 - i] : 0u;
        m16[i] = aa > bb ? aa : bb;
    }
    #pragma unroll
    for (int g = 8; g >= 1; g >>= 1) {      // bitonic merge, descending
        #pragma unroll
        for (int i = 0; i < 16; ++i) {
            if (!(i & g)) {
                unsigned x0 = m16[i], x1 = m16[i + g];
                m16[i]     = x0 > x1 ? x0 : x1;
                m16[i + g] = x0 > x1 ? x1 : x0;
            }
        }
    }
    #pragma unroll
    for (int i = 0; i < NK; ++i) o12[i] = m16[i];
}

// ---- shared conv body: 2048 consecutive floats -> (hi,lo) bf16 -------------
__device__ __forceinline__ void conv_body(const float* __restrict__ src,
        __bf16* __restrict__ dhi, __bf16* __restrict__ dlo, int i)
{
    float4 a = *(const float4*)(src + i);
    float4 c = *(const float4*)(src + i + 4);
    float av[8] = {a.x, a.y, a.z, a.w, c.x, c.y, c.z, c.w};
    __bf16 h[8], l[8];
    #pragma unroll
    for (int j = 0; j < 8; ++j) {
        h[j] = (__bf16)av[j];
        l[j] = (__bf16)(av[j] - (float)h[j]);
    }
    *(float4*)(dhi + i) = *(float4*)h;
    *(float4*)(dlo + i) = *(float4*)l;
}

// ---------------- K_A: FUSED convX + convW + partial-mean (one launch) -------
// blocks [0,4096): x -> (xhi,xlo); [4096,4128): Wq/Wk -> (Whi,Wlo);
// [4128,4256): per-(b,tch,dblk) column partial sums -> meansum2 (NO atomics,
// NO memset: each block owns a private slot; select sums the 16 partials).
__global__ __launch_bounds__(256) void prep_kernel(const float* __restrict__ x,
        const float* __restrict__ Wq, const float* __restrict__ Wk,
        __bf16* __restrict__ xhi, __bf16* __restrict__ xlo,
        __bf16* __restrict__ Whi, __bf16* __restrict__ Wlo,
        float* __restrict__ meansum2)
{
    int g = blockIdx.x;
    if (g < 4096) {
        conv_body(x, xhi, xlo, (g * 256 + threadIdx.x) << 3);
    } else if (g < 4128) {
        int gw = g - 4096;
        const float* src = (gw < 16) ? Wq : Wk;
        __bf16* dhi = Whi + ((gw < 16) ? 0 : 32 * D);
        __bf16* dlo = Wlo + ((gw < 16) ? 0 : 32 * D);
        conv_body(src, dhi, dlo, ((gw & 15) * 256 + threadIdx.x) << 3);
    } else {
        int gm = g - 4128;               // B * 4 dblk * 16 tch = 128 blocks
        int b = gm >> 6;
        int rem = gm & 63;
        int dblk = rem >> 4;
        int tch = rem & 15;
        int d = dblk * 256 + threadIdx.x;
        const float* xp = x + (b * T + tch * 256) * D + d;
        float s = 0.f;
        #pragma unroll 8
        for (int it = 0; it < 256; ++it) s += xp[it * D];
        meansum2[(((b << 4) + tch) << 10) + d] = s;   // private slot, plain store
    }
}

// ---------------- K_B: FUSED qk projection + topk sim GEMM (one launch) ------
// blocks [0,128): qk (split-bf16 MFMA, 64-row blocks, 20KB of smem);
// blocks [128,1184): topk with bijective XCD swizzle (1056 = 8*132):
//   l = (p%8)*132 + p/8 -> each XCD walks 132 contiguous triangle indices
//   (A-row panels L2-resident). topk internals = r7's verified structure:
//   A triple-buffered + B double-buffered (40960 B, 4 blk/CU), counted
//   vmcnt(2), ONE barrier/iter; in-wave quarter scan + shfl_xor merges.
__global__ __launch_bounds__(256, 4) void qk_topk_kernel(
        const __bf16* __restrict__ xhi, const __bf16* __restrict__ xlo,
        const __bf16* __restrict__ Whi, const __bf16* __restrict__ Wlo,
        float* __restrict__ qo, float* __restrict__ ko,
        unsigned* __restrict__ pkey)
{
    __shared__ __align__(16) char smem[40960];
    int tid = threadIdx.x;
    int w = tid >> 6, lane = tid & 63;
    int fr = lane & 15, fq = lane >> 4;

    if (blockIdx.x < 128) {
        // ---------------- qk body (r7 verbatim) ----------------
        __bf16* sAhi = (__bf16*)smem;          // 64 x 40
        __bf16* sAlo = sAhi + 2560;
        __bf16* sBhi = sAhi + 5120;            // 64 x 40
        __bf16* sBlo = sAhi + 7680;

        int m0 = blockIdx.x << 6;
        int arow = tid >> 2, aq = tid & 3;     // 4 chunks of 8 bf16 per row
        const __bf16* gAh = xhi + (size_t)(m0 + arow) * D + aq * 8;
        const __bf16* gAl = xlo + (size_t)(m0 + arow) * D + aq * 8;
        const __bf16* gBh = Whi + arow * D + aq * 8;
        const __bf16* gBl = Wlo + arow * D + aq * 8;

        f32x4 acc[4];
        #pragma unroll
        for (int j = 0; j < 4; ++j) acc[j] = (f32x4){0.f, 0.f, 0.f, 0.f};

        float4 a0 = *(const float4*)(gAh);
        float4 a1 = *(const float4*)(gAl);
        float4 b0 = *(const float4*)(gBh);
        float4 b1 = *(const float4*)(gBl);

        int sa = arow * 40 + aq * 8;

        for (int kc = 0; kc < 32; ++kc) {
            __syncthreads();
            *(float4*)(sAhi + sa) = a0;
            *(float4*)(sAlo + sa) = a1;
            *(float4*)(sBhi + sa) = b0;
            *(float4*)(sBlo + sa) = b1;
            __syncthreads();
            if (kc + 1 < 32) {
                int k0 = (kc + 1) << 5;
                a0 = *(const float4*)(gAh + k0);
                a1 = *(const float4*)(gAl + k0);
                b0 = *(const float4*)(gBh + k0);
                b1 = *(const float4*)(gBl + k0);
            }
            int r = (w << 4) + fr;
            bf16x8 fah = *(const bf16x8*)(sAhi + r * 40 + fq * 8);
            bf16x8 fal = *(const bf16x8*)(sAlo + r * 40 + fq * 8);
            bf16x8 fbh[4], fbl[4];
            #pragma unroll
            for (int j = 0; j < 4; ++j) {
                int rb = j * 16 + fr;
                fbh[j] = *(const bf16x8*)(sBhi + rb * 40 + fq * 8);
                fbl[j] = *(const bf16x8*)(sBlo + rb * 40 + fq * 8);
            }
            #pragma unroll
            for (int j = 0; j < 4; ++j) {
                acc[j] = __builtin_amdgcn_mfma_f32_16x16x32_bf16(fah, fbh[j], acc[j], 0, 0, 0);
                acc[j] = __builtin_amdgcn_mfma_f32_16x16x32_bf16(fah, fbl[j], acc[j], 0, 0, 0);
                acc[j] = __builtin_amdgcn_mfma_f32_16x16x32_bf16(fal, fbh[j], acc[j], 0, 0, 0);
            }
        }
        // writeout: C layout col=lane&15, row=fq*4+reg
        int grow0 = m0 + (w << 4) + (fq << 2);
        #pragma unroll
        for (int j = 0; j < 4; ++j) {
            int gn = j * 16 + fr;
            float* dst = (gn < 32) ? (qo + grow0 * DH + gn)
                                   : (ko + grow0 * DH + gn - 32);
            dst[0]      = acc[j][0];
            dst[DH]     = acc[j][1];
            dst[2 * DH] = acc[j][2];
            dst[3 * DH] = acc[j][3];
        }
        return;
    }

    // ---------------- topk body (r7 structure + XCD swizzle) ----------------
    __bf16* stg = (__bf16*)smem;   // A bufs @ 0,4096,8192; B bufs @ 12288,16384
    float* Sbuf = (float*)smem;    // 64 x 129 fp32 = 33024 B (post-loop)

    int p = blockIdx.x - 128;
    int swz = (p & 7) * 132 + (p >> 3);     // bijective: 1056 = 8*132
    int b = swz / NBLK;
    int l = swz - b * NBLK;
    int rt = (int)((sqrtf(8.f * l + 1.f) - 1.f) * 0.5f);
    while ((rt + 1) * (rt + 2) / 2 <= l) ++rt;
    while (rt * (rt + 1) / 2 > l) --rt;
    int ct = l - rt * (rt + 1) / 2;
    int r0 = rt << 7, c0 = ct << 7;
    int base = b * T;

    int wr = (w >> 1) << 6, wc = (w & 1) << 6;
    bool active = !(rt == ct && w == 1);   // diag block, fully non-causal quadrant
    int fqs = (fq ^ ((fr >> 1) & 3)) << 3; // swizzled 16B-slot (bf16 offset)

    // staging: lane i of wave w covers (row 16w + (i>>2), swizzled 16B-chunk)
    int lrow = lane >> 2;
    int lcq = (((lane & 3) ^ ((lane >> 3) & 3)) << 3);   // pre-swizzled source slot
    const __bf16* gA = xhi + (size_t)(base + r0) * D;
    const __bf16* gB = xhi + (size_t)(base + c0) * D;
    const __bf16* gA0 = gA + (size_t)((w << 4) + lrow) * D + lcq;
    const __bf16* gA1 = gA0 + (size_t)64 * D;
    const __bf16* gB0 = gB + (size_t)((w << 4) + lrow) * D + lcq;
    const __bf16* gB1 = gB0 + (size_t)64 * D;

    f32x4 acc[4][4];
    #pragma unroll
    for (int i = 0; i < 4; ++i)
        #pragma unroll
        for (int j = 0; j < 4; ++j) acc[i][j] = (f32x4){0.f, 0.f, 0.f, 0.f};

#define ISSUE_A(BUFBASE, KO) do { \
    __bf16* bA_ = (BUFBASE); \
    __builtin_amdgcn_global_load_lds((const AS1 unsigned int*)(gA0 + (KO)), \
        (AS3 unsigned int*)(bA_ + (w << 9)), 16, 0, 0); \
    __builtin_amdgcn_global_load_lds((const AS1 unsigned int*)(gA1 + (KO)), \
        (AS3 unsigned int*)(bA_ + 2048 + (w << 9)), 16, 0, 0); \
} while (0)
#define ISSUE_B(BUFBASE, KO) do { \
    __bf16* bB_ = (BUFBASE); \
    __builtin_amdgcn_global_load_lds((const AS1 unsigned int*)(gB0 + (KO)), \
        (AS3 unsigned int*)(bB_ + (w << 9)), 16, 0, 0); \
    __builtin_amdgcn_global_load_lds((const AS1 unsigned int*)(gB1 + (KO)), \
        (AS3 unsigned int*)(bB_ + 2048 + (w << 9)), 16, 0, 0); \
} while (0)

    // prologue, ordinal [B(0), A(0), A(1)]
    ISSUE_B(stg + 12288, 0);
    ISSUE_A(stg, 0);
    ISSUE_A(stg + 4096, 32);

    int asel = 0, isel = 2;
    for (int kc = 0; kc < 32; ++kc) {
        // steady outstanding at wait: [A(k) 2, B(k) 2, A(k+1) 2] (oldest->newest)
        // vmcnt(2) drains A(k), B(k); A(k+1)'s 2 loads stay in flight.
        if (kc < 31) { asm volatile("s_waitcnt vmcnt(2)" ::: "memory"); }
        else         { asm volatile("s_waitcnt vmcnt(0)" ::: "memory"); }
        __builtin_amdgcn_s_barrier();      // buffers for tile kc visible
        asm volatile("" ::: "memory");
        if (kc + 1 < 32)                   // B(k+1) into bbuf[(k+1)&1] (read iter k-1)
            ISSUE_B(stg + 12288 + (((kc + 1) & 1) << 12), (kc + 1) << 5);
        if (kc + 2 < 32) {                 // A(k+2) into abuf[(k+2)%3] (read iter k-1)
            ISSUE_A(stg + (isel << 12), (kc + 2) << 5);
            isel = (isel == 2) ? 0 : isel + 1;
        }
        if (active) {
            const __bf16* cA = stg + (asel << 12);
            const __bf16* cB = stg + 12288 + ((kc & 1) << 12);
            bf16x8 ah[4], bh[4];
            #pragma unroll
            for (int i = 0; i < 4; ++i) {
                int ar = wr + i * 16 + fr;
                ah[i] = *(const bf16x8*)(cA + ar * 32 + fqs);
                int bc = wc + i * 16 + fr;
                bh[i] = *(const bf16x8*)(cB + bc * 32 + fqs);
            }
            #pragma unroll
            for (int i = 0; i < 4; ++i)
                #pragma unroll
                for (int j = 0; j < 4; ++j)
                    acc[i][j] = __builtin_amdgcn_mfma_f32_16x16x32_bf16(ah[i], bh[j], acc[i][j], 0, 0, 0);
        }
        asel = (asel == 2) ? 0 : asel + 1;
    }
#undef ISSUE_A
#undef ISSUE_B

    int cr = fq << 2, cc = fr;             // C layout: col=lane&15, row=fq*4+reg
    int q = lane >> 4;                     // scan quarter
    #pragma unroll
    for (int phase = 0; phase < 2; ++phase) {
        __syncthreads();                   // staging reads / prior phase done
        if ((w >> 1) == phase) {           // waves owning rows [phase*64, +64)
            #pragma unroll
            for (int i = 0; i < 4; ++i)
                #pragma unroll
                for (int j = 0; j < 4; ++j) {
                    float* sp = Sbuf + (i * 16 + cr) * 129 + wc + j * 16 + cc;
                    sp[0]       = acc[i][j][0];
                    sp[129]     = acc[i][j][1];
                    sp[2 * 129] = acc[i][j][2];
                    sp[3 * 129] = acc[i][j][3];
                }
        }
        __syncthreads();
        // in-wave scan: wave w owns Sbuf rows w*16 + (lane&15); quarter q
        {
            int sr = (w << 4) + (lane & 15);
            int gt = r0 + (phase << 6) + sr;
            int cmax = gt - c0;
            if (cmax > 128) cmax = 128;
            if (cmax < 0) cmax = 0;
            int h0 = q << 5;
            int hmax = cmax < (h0 + 32) ? cmax : (h0 + 32);
            unsigned key[NK];
            #pragma unroll
            for (int i = 0; i < NK; ++i) key[i] = 0u;
            const float* Srow = Sbuf + sr * 129;
            #pragma unroll
            for (int mb = 0; mb < 4; ++mb) {           // bank-rotated batches
                int cb = h0 + (((mb + q) & 3) << 3);
                float v[8];
                #pragma unroll
                for (int j = 0; j < 8; ++j) v[j] = Srow[cb + j];   // 8 in flight
                #pragma unroll
                for (int j = 0; j < 8; ++j) {
                    int c = cb + j;
                    unsigned u = mono32(v[j]);
                    unsigned tk = (c < hmax) ? ((u & 0xFFFFFF80u) | (unsigned)(127 - c)) : 0u;
                    #pragma unroll
                    for (int i = 0; i < NK; ++i) {      // branchless sorted insert
                        unsigned hi = key[i] > tk ? key[i] : tk;
                        unsigned lo = key[i] > tk ? tk : key[i];
                        key[i] = hi; tk = lo;
                    }
                }
            }
            // merge quarters: lanes ^16 then ^32 (top-12 sets order-independent)
            #pragma unroll
            for (int lvl = 0; lvl < 2; ++lvl) {
                int xm = 16 << lvl;
                unsigned o12[NK], m12[NK];
                #pragma unroll
                for (int i = 0; i < NK; ++i) o12[i] = __shfl_xor(key[i], xm);
                merge12(key, o12, m12);
                #pragma unroll
                for (int i = 0; i < NK; ++i) key[i] = m12[i];
            }
            // store: lanes q<3 each write 4 keys as one dwordx4
            if (q < 3) {
                u32x4 ov;
                #pragma unroll
                for (int j = 0; j < 4; ++j) {
                    unsigned k0 = (q == 0) ? key[j] : (q == 1) ? key[4 + j] : key[8 + j];
                    // repack: value20 | (4095 - gcol), gcol = c0 + 127 - (k0&127)
                    ov[j] = k0 ? ((k0 & 0xFFFFF000u) | ((k0 & 127u) + (unsigned)(3968 - c0))) : 0u;
                }
                *(u32x4*)(pkey + (size_t)(base + gt) * CPR + ct * NK + (q << 2)) = ov;
            }
        }
    }
}

// ---------------- K_C: FUSED wave-per-row selection + message + gelu ---------
// u32 packed-key candidates; 12 DPP extract-max passes (winners wave-uniform
// in SGPRs); scalar-addressed exact re-rank with DPP sum reduce; u64 exact
// top-8 insert; DPP 8-group score reduce. t==0 rows sum the 16 meansum2
// partials inline (2 waves in the whole grid).
__global__ __launch_bounds__(256) void select_msg_kernel(const float* __restrict__ x,
        const float* __restrict__ q, const float* __restrict__ k,
        const float* __restrict__ meansum2,
        const unsigned* __restrict__ pkey,
        const float* __restrict__ gain, const float* __restrict__ bias,
        const float* __restrict__ plm, const float* __restrict__ pls,
        float* __restrict__ out)
{
    int tid = threadIdx.x;
    int w = tid >> 6, lane = tid & 63;
    int rid = (blockIdx.x << 2) + w;         // global row b*T+t
    int b = rid >> 12, t = rid & (T - 1);
    int ncand = NK * ((t + 127) >> 7);

    // candidate loads (all in flight)
    unsigned cv[6];
    #pragma unroll
    for (int u = 0; u < 6; ++u) {
        int cid = lane + (u << 6);
        cv[u] = (cid < ncand) ? pkey[(size_t)rid * CPR + cid] : 0u;
    }
    // prefetch xt fragments (independent of merge)
    const float* xt = x + (size_t)rid * D;
    float4 xt4[4];
    #pragma unroll
    for (int c = 0; c < 4; ++c)
        xt4[c] = *(const float4*)(xt + (c << 8) + (lane << 2));

    // 12 DPP extract-max passes -> wave-uniform winners (keys unique: idx in key)
    unsigned skey[NK]; int sgid[NK];
    #pragma unroll
    for (int i = 0; i < NK; ++i) {
        unsigned m = cv[0];
        #pragma unroll
        for (int u = 1; u < 6; ++u) m = m > cv[u] ? m : cv[u];
        m = dpp_umax_bcast(m);               // uniform (SGPR)
        skey[i] = m;
        sgid[i] = 4095 - (int)(m & 4095u);
        #pragma unroll
        for (int u = 0; u < 6; ++u) cv[u] = (cv[u] == m) ? 0u : cv[u];
    }

    // exact fp32 re-rank: 3 batches of 4; uniform row bases, DPP sum reduce
    float ex[NK];
    #pragma unroll
    for (int batch = 0; batch < 3; ++batch) {
        float4 rv[4][4];
        #pragma unroll
        for (int s = 0; s < 4; ++s) {
            int i = batch * 4 + s;
            int row = (skey[i] != 0u) ? sgid[i] : 0;
            const float* xj = x + (size_t)((b << 12) + row) * D;
            #pragma unroll
            for (int c = 0; c < 4; ++c)
                rv[s][c] = *(const float4*)(xj + (c << 8) + (lane << 2));
        }
        #pragma unroll
        for (int s = 0; s < 4; ++s) {
            float ss = 0.f;
            #pragma unroll
            for (int c = 0; c < 4; ++c)
                ss += xt4[c].x * rv[s][c].x + xt4[c].y * rv[s][c].y
                    + xt4[c].z * rv[s][c].z + xt4[c].w * rv[s][c].w;
            ex[batch * 4 + s] = dpp_fsum_bcast(ss);   // uniform
        }
    }

    // exact top-8 via u64 packed keys: (mono(value) << 12) | (4095 - idx)
    unsigned long long top8[8];
    #pragma unroll
    for (int r = 0; r < 8; ++r) top8[r] = 0ull;
    #pragma unroll
    for (int i = 0; i < NK; ++i) {
        unsigned u = mono32(ex[i]);
        unsigned long long t64 = (skey[i] != 0u)
            ? ((((unsigned long long)u) << 12) | (unsigned long long)(4095 - sgid[i]))
            : 0ull;
        #pragma unroll
        for (int r = 0; r < 8; ++r) {       // branchless sorted insert
            unsigned long long hi = (t64 > top8[r]) ? t64 : top8[r];
            unsigned long long lo = (t64 > top8[r]) ? top8[r] : t64;
            top8[r] = hi; t64 = lo;
        }
    }
    bool vld[8]; int bidx[8];
    #pragma unroll
    for (int i = 0; i < 8; ++i) {
        vld[i]  = top8[i] != 0ull;
        bidx[i] = 4095 - (int)(top8[i] & 4095ull);
    }

    // scores: lanes 8i..8i+7 compute dot(q[t], k[sel_i]); key via cndmask tree
    int i8 = lane >> 3, e = lane & 7;
    unsigned long long kk = (i8 & 4)
        ? ((i8 & 2) ? ((i8 & 1) ? top8[7] : top8[6]) : ((i8 & 1) ? top8[5] : top8[4]))
        : ((i8 & 2) ? ((i8 & 1) ? top8[3] : top8[2]) : ((i8 & 1) ? top8[1] : top8[0]));
    bool v8 = kk != 0ull;
    int g8 = v8 ? (4095 - (int)(kk & 4095ull)) : 0;
    float4 qv = *(const float4*)(q + (size_t)rid * DH + (e << 2));
    float4 kv = *(const float4*)(k + (size_t)((b << 12) + g8) * DH + (e << 2));
    float p = qv.x * kv.x + qv.y * kv.y + qv.z * kv.z + qv.w * kv.w;
    p = dpp_gsum8(p);
    p *= 0.17677669529663687f;               // 1/sqrt(32)

    float sc[8];
    #pragma unroll
    for (int i = 0; i < 8; ++i)
        sc[i] = __int_as_float(__builtin_amdgcn_readlane(__float_as_int(p), i << 3));

    float m = -INFINITY; int cnt = 0;
    #pragma unroll
    for (int i = 0; i < 8; ++i)
        if (vld[i]) { ++cnt; if (sc[i] > m) m = sc[i]; }

    float wgt[8]; float Z = 0.f; int gsel[8];
    #pragma unroll
    for (int i = 0; i < 8; ++i) {
        wgt[i] = vld[i] ? expf(sc[i] - m) : 0.f;
        Z += wgt[i];
        gsel[i] = vld[i] ? ((b << 12) + bidx[i]) : (b << 12);
    }
    float invZ = (cnt > 0) ? 1.f / Z : 0.f;
    #pragma unroll
    for (int i = 0; i < 8; ++i) wgt[i] *= invZ;

    // ---- fused epilogue: msg accumulation on lane's 16 dims + gelu ----
    float mix   = 1.f / (1.f + expf(-plm[0]));
    float scale = log1pf(expf(pls[0])) + 0.01f;
    const float onemix = 1.f - mix;

    float4 msg4[4];
    if (cnt == 0) {                          // t==0: uniform attention over ALL T
        #pragma unroll
        for (int c = 0; c < 4; ++c) {
            int d0 = (c << 8) + (lane << 2);
            float4 a4 = (float4){0.f, 0.f, 0.f, 0.f};
            #pragma unroll
            for (int tch = 0; tch < 16; ++tch) {
                float4 ms = *(const float4*)(meansum2 + (((b << 4) + tch) << 10) + d0);
                a4.x += ms.x; a4.y += ms.y; a4.z += ms.z; a4.w += ms.w;
            }
            msg4[c].x = a4.x * (1.f / (float)T); msg4[c].y = a4.y * (1.f / (float)T);
            msg4[c].z = a4.z * (1.f / (float)T); msg4[c].w = a4.w * (1.f / (float)T);
        }
    } else {
        #pragma unroll
        for (int c = 0; c < 4; ++c) msg4[c] = (float4){0.f, 0.f, 0.f, 0.f};
        #pragma unroll
        for (int g = 0; g < 2; ++g) {        // 2 batches of 4 rows (L2-hot re-read)
            float4 rv[4][4];
            #pragma unroll
            for (int s = 0; s < 4; ++s) {
                const float* xj = x + (size_t)gsel[g * 4 + s] * D;
                #pragma unroll
                for (int c = 0; c < 4; ++c)
                    rv[s][c] = *(const float4*)(xj + (c << 8) + (lane << 2));
            }
            #pragma unroll
            for (int s = 0; s < 4; ++s) {    // preserves i=0..7 summation order
                float wi = wgt[g * 4 + s];
                #pragma unroll
                for (int c = 0; c < 4; ++c) {
                    msg4[c].x += wi * rv[s][c].x; msg4[c].y += wi * rv[s][c].y;
                    msg4[c].z += wi * rv[s][c].z; msg4[c].w += wi * rv[s][c].w;
                }
            }
        }
    }
    #pragma unroll
    for (int c = 0; c < 4; ++c) {
        int d0 = (c << 8) + (lane << 2);
        float4 g4 = *(const float4*)(gain + d0);
        float4 b4 = *(const float4*)(bias + d0);
        float4 xv = xt4[c];
        float zi[4] = {
            (mix * xv.x + onemix * msg4[c].x) * g4.x + b4.x,
            (mix * xv.y + onemix * msg4[c].y) * g4.y + b4.y,
            (mix * xv.z + onemix * msg4[c].z) * g4.z + b4.z,
            (mix * xv.w + onemix * msg4[c].w) * g4.w + b4.w };
        float4 o4;
        o4.x = 0.5f * zi[0] * (1.f + erff(zi[0] * 0.70710678118654752f)) * scale;
        o4.y = 0.5f * zi[1] * (1.f + erff(zi[1] * 0.70710678118654752f)) * scale;
        o4.z = 0.5f * zi[2] * (1.f + erff(zi[2] * 0.70710678118654752f)) * scale;
        o4.w = 0.5f * zi[3] * (1.f + erff(zi[3] * 0.70710678118654752f)) * scale;
        *(float4*)(out + (size_t)rid * D + d0) = o4;
    }
}

extern "C" void kernel_launch(void* const* d_in, const int* in_sizes, int n_in,
                              void* d_out, int out_size, void* d_ws, size_t ws_size,
                              hipStream_t stream)
{
    const float* x    = (const float*)d_in[0];
    const float* Wq   = (const float*)d_in[1];
    const float* Wk   = (const float*)d_in[2];
    const float* gain = (const float*)d_in[3];
    const float* bias = (const float*)d_in[4];
    const float* plm  = (const float*)d_in[5];
    const float* pls  = (const float*)d_in[6];
    float* out = (float*)d_out;

    float* ws       = (float*)d_ws;
    float* q        = ws;                        // 262144
    float* k        = ws + 262144;               // 262144
    float* meansum2 = ws + 524288;               // B*16*1024 = 32768
    unsigned* pkey  = (unsigned*)(ws + 557056);  // B*T*CPR u32 = 3145728 slots
    __bf16* xhi     = (__bf16*)(ws + 3702784);   // B*T*D bf16
    __bf16* xlo     = xhi + (size_t)B * T * D;
    __bf16* Whi     = xlo + (size_t)B * T * D;   // 64*1024 bf16
    __bf16* Wlo     = Whi + 64 * D;
    // total ws use: ~49 MB

    prep_kernel<<<4256, 256, 0, stream>>>(x, Wq, Wk, xhi, xlo, Whi, Wlo, meansum2);
    qk_topk_kernel<<<128 + B * NBLK, 256, 0, stream>>>(xhi, xlo, Whi, Wlo, q, k, pkey);
    select_msg_kernel<<<B * T / 4, 256, 0, stream>>>(x, q, k, meansum2, pkey,
                                                     gain, bias, plm, pls, out);
}

// Round 9
// 230.977 us; speedup vs baseline: 1.2819x; 1.0104x over previous
//
#include <hip/hip_runtime.h>
#include <math.h>

#define B 2
#define T 4096
#define D 1024
#define DH 32
#define TNB 32        // 128-row tiles per batch
#define NBLK 528      // TNB*(TNB+1)/2 causal tile pairs
#define NK 12         // per-chunk candidates kept (safety margin over 8)
#define CPR (32*NK)   // candidates per row = 384

typedef __bf16 bf16x8 __attribute__((ext_vector_type(8)));
typedef float f32x4 __attribute__((ext_vector_type(4)));
typedef unsigned u32x4 __attribute__((ext_vector_type(4)));

#define AS1 __attribute__((address_space(1)))
#define AS3 __attribute__((address_space(3)))

// monotone f32 -> u32 (order-preserving); branchless
__device__ __forceinline__ unsigned mono32(float v) {
    unsigned u = __float_as_uint(v);
    u ^= ((unsigned)((int)u >> 31)) | 0x80000000u;
    return u;
}

// ---- wave-wide u32 max, result broadcast via readlane(63) (uniform/SGPR) ----
__device__ __forceinline__ unsigned dpp_umax_bcast(unsigned v) {
    #define DPPMAX(CTRL) { unsigned t_ = (unsigned)__builtin_amdgcn_update_dpp(0, (int)v, CTRL, 0xF, 0xF, true); v = v > t_ ? v : t_; }
    DPPMAX(0x111) DPPMAX(0x112) DPPMAX(0x114) DPPMAX(0x118)   // row_shr 1,2,4,8
    DPPMAX(0x142) DPPMAX(0x143)                               // row_bcast 15,31
    #undef DPPMAX
    return (unsigned)__builtin_amdgcn_readlane((int)v, 63);
}
// ---- wave-wide f32 sum, result broadcast via readlane(63) (uniform/SGPR) ----
__device__ __forceinline__ float dpp_fsum_bcast(float v) {
    #define DPPADD(CTRL) { int t_ = __builtin_amdgcn_update_dpp(0, __float_as_int(v), CTRL, 0xF, 0xF, true); v += __int_as_float(t_); }
    DPPADD(0x111) DPPADD(0x112) DPPADD(0x114) DPPADD(0x118)
    DPPADD(0x142) DPPADD(0x143)
    #undef DPPADD
    return __int_as_float(__builtin_amdgcn_readlane(__float_as_int(v), 63));
}
// ---- sum across each aligned 8-lane group (all lanes get the sum) ----
__device__ __forceinline__ float dpp_gsum8(float p) {
    { int t_ = __builtin_amdgcn_update_dpp(0, __float_as_int(p), 0x0B1, 0xF, 0xF, true); p += __int_as_float(t_); } // quad_perm xor1
    { int t_ = __builtin_amdgcn_update_dpp(0, __float_as_int(p), 0x04E, 0xF, 0xF, true); p += __int_as_float(t_); } // quad_perm xor2
    { int t_ = __builtin_amdgcn_update_dpp(0, __float_as_int(p), 0x141, 0xF, 0xF, true); p += __int_as_float(t_); } // row_half_mirror (xor7)
    return p;
}

// ---- bitonic merge of two sorted-desc 12-lists (packed unique keys) ----
__device__ __forceinline__ void merge12(const unsigned* a12, const unsigned* b12,
                                        unsigned* o12) {
    unsigned m16[16];
    #pragma unroll
    for (int i = 0; i < 16; ++i) {          // bitonic split, keep top-16
        unsigned aa = (i < NK) ? a12[i] : 0u;
        unsigned bb = (15 - i < NK) ? b12[15 - i] : 0u;
        m16[i] = aa > bb ? aa : bb;
    }
    #pragma unroll
    for (int g = 8; g >= 1; g >>= 1) {      // bitonic merge, descending
        #pragma unroll
        for (int i = 0; i < 16; ++i) {
            if (!(i & g)) {
                unsigned x0 = m16[i], x1 = m16[i + g];
                m16[i]     = x0 > x1 ? x0 : x1;
                m16[i + g] = x0 > x1 ? x1 : x0;
            }
        }
    }
    #pragma unroll
    for (int i = 0; i < NK; ++i) o12[i] = m16[i];
}

// ---- shared conv body: 2048 consecutive floats -> (hi,lo) bf16 -------------
__device__ __forceinline__ void conv_body(const float* __restrict__ src,
        __bf16* __restrict__ dhi, __bf16* __restrict__ dlo, int i)
{
    float4 a = *(const float4*)(src + i);
    float4 c = *(const float4*)(src + i + 4);
    float av[8] = {a.x, a.y, a.z, a.w, c.x, c.y, c.z, c.w};
    __bf16 h[8], l[8];
    #pragma unroll
    for (int j = 0; j < 8; ++j) {
        h[j] = (__bf16)av[j];
        l[j] = (__bf16)(av[j] - (float)h[j]);
    }
    *(float4*)(dhi + i) = *(float4*)h;
    *(float4*)(dlo + i) = *(float4*)l;
}

// ---------------- K_A: FUSED convX + convW + partial-mean (one launch) -------
// blocks [0,4096): x -> (xhi,xlo); [4096,4128): Wq/Wk -> (Whi,Wlo);
// [4128,4256): per-(b,tch,dblk) column partial sums -> meansum2 (NO atomics,
// NO memset: each block owns a private slot; select sums the 16 partials).
__global__ __launch_bounds__(256) void prep_kernel(const float* __restrict__ x,
        const float* __restrict__ Wq, const float* __restrict__ Wk,
        __bf16* __restrict__ xhi, __bf16* __restrict__ xlo,
        __bf16* __restrict__ Whi, __bf16* __restrict__ Wlo,
        float* __restrict__ meansum2)
{
    int g = blockIdx.x;
    if (g < 4096) {
        conv_body(x, xhi, xlo, (g * 256 + threadIdx.x) << 3);
    } else if (g < 4128) {
        int gw = g - 4096;
        const float* src = (gw < 16) ? Wq : Wk;
        __bf16* dhi = Whi + ((gw < 16) ? 0 : 32 * D);
        __bf16* dlo = Wlo + ((gw < 16) ? 0 : 32 * D);
        conv_body(src, dhi, dlo, ((gw & 15) * 256 + threadIdx.x) << 3);
    } else {
        int gm = g - 4128;               // B * 4 dblk * 16 tch = 128 blocks
        int b = gm >> 6;
        int rem = gm & 63;
        int dblk = rem >> 4;
        int tch = rem & 15;
        int d = dblk * 256 + threadIdx.x;
        const float* xp = x + (b * T + tch * 256) * D + d;
        float s = 0.f;
        #pragma unroll 8
        for (int it = 0; it < 256; ++it) s += xp[it * D];
        meansum2[(((b << 4) + tch) << 10) + d] = s;   // private slot, plain store
    }
}

// ---------------- K_B: FUSED qk projection + topk sim GEMM (one launch) ------
// blocks [0,128): qk (split-bf16 MFMA, 64-row blocks, 20KB of smem);
// blocks [128,1184): topk with bijective XCD swizzle (1056 = 8*132).
// topk K-loop = r7/r8 verified structure: A triple-buffered + B double-
// buffered (40960 B, 4 blk/CU), counted vmcnt(2), ONE barrier/iter.
// Epilogue: SINGLE-phase bf16 Sbuf [128][130] (33280 B): one write pass,
// one scan pass (2 barriers vs 4; scan read bytes halved). Per-lane 64-col
// half-scan + 1x shfl_xor(32)+merge12; half-0 lane stores 12 keys (3x dwordx4).
// Output: value[31:12] | (4095 - gidx).
__global__ __launch_bounds__(256, 4) void qk_topk_kernel(
        const __bf16* __restrict__ xhi, const __bf16* __restrict__ xlo,
        const __bf16* __restrict__ Whi, const __bf16* __restrict__ Wlo,
        float* __restrict__ qo, float* __restrict__ ko,
        unsigned* __restrict__ pkey)
{
    __shared__ __align__(16) char smem[40960];
    int tid = threadIdx.x;
    int w = tid >> 6, lane = tid & 63;
    int fr = lane & 15, fq = lane >> 4;

    if (blockIdx.x < 128) {
        // ---------------- qk body (r8 verbatim) ----------------
        __bf16* sAhi = (__bf16*)smem;          // 64 x 40
        __bf16* sAlo = sAhi + 2560;
        __bf16* sBhi = sAhi + 5120;            // 64 x 40
        __bf16* sBlo = sAhi + 7680;

        int m0 = blockIdx.x << 6;
        int arow = tid >> 2, aq = tid & 3;     // 4 chunks of 8 bf16 per row
        const __bf16* gAh = xhi + (size_t)(m0 + arow) * D + aq * 8;
        const __bf16* gAl = xlo + (size_t)(m0 + arow) * D + aq * 8;
        const __bf16* gBh = Whi + arow * D + aq * 8;
        const __bf16* gBl = Wlo + arow * D + aq * 8;

        f32x4 acc[4];
        #pragma unroll
        for (int j = 0; j < 4; ++j) acc[j] = (f32x4){0.f, 0.f, 0.f, 0.f};

        float4 a0 = *(const float4*)(gAh);
        float4 a1 = *(const float4*)(gAl);
        float4 b0 = *(const float4*)(gBh);
        float4 b1 = *(const float4*)(gBl);

        int sa = arow * 40 + aq * 8;

        for (int kc = 0; kc < 32; ++kc) {
            __syncthreads();
            *(float4*)(sAhi + sa) = a0;
            *(float4*)(sAlo + sa) = a1;
            *(float4*)(sBhi + sa) = b0;
            *(float4*)(sBlo + sa) = b1;
            __syncthreads();
            if (kc + 1 < 32) {
                int k0 = (kc + 1) << 5;
                a0 = *(const float4*)(gAh + k0);
                a1 = *(const float4*)(gAl + k0);
                b0 = *(const float4*)(gBh + k0);
                b1 = *(const float4*)(gBl + k0);
            }
            int r = (w << 4) + fr;
            bf16x8 fah = *(const bf16x8*)(sAhi + r * 40 + fq * 8);
            bf16x8 fal = *(const bf16x8*)(sAlo + r * 40 + fq * 8);
            bf16x8 fbh[4], fbl[4];
            #pragma unroll
            for (int j = 0; j < 4; ++j) {
                int rb = j * 16 + fr;
                fbh[j] = *(const bf16x8*)(sBhi + rb * 40 + fq * 8);
                fbl[j] = *(const bf16x8*)(sBlo + rb * 40 + fq * 8);
            }
            #pragma unroll
            for (int j = 0; j < 4; ++j) {
                acc[j] = __builtin_amdgcn_mfma_f32_16x16x32_bf16(fah, fbh[j], acc[j], 0, 0, 0);
                acc[j] = __builtin_amdgcn_mfma_f32_16x16x32_bf16(fah, fbl[j], acc[j], 0, 0, 0);
                acc[j] = __builtin_amdgcn_mfma_f32_16x16x32_bf16(fal, fbh[j], acc[j], 0, 0, 0);
            }
        }
        // writeout: C layout col=lane&15, row=fq*4+reg
        int grow0 = m0 + (w << 4) + (fq << 2);
        #pragma unroll
        for (int j = 0; j < 4; ++j) {
            int gn = j * 16 + fr;
            float* dst = (gn < 32) ? (qo + grow0 * DH + gn)
                                   : (ko + grow0 * DH + gn - 32);
            dst[0]      = acc[j][0];
            dst[DH]     = acc[j][1];
            dst[2 * DH] = acc[j][2];
            dst[3 * DH] = acc[j][3];
        }
        return;
    }

    // ---------------- topk body ----------------
    __bf16* stg = (__bf16*)smem;   // A bufs @ 0,4096,8192; B bufs @ 12288,16384
    __bf16* Sb  = (__bf16*)smem;   // post-loop: bf16 [128][130] = 33280 B

    int p = blockIdx.x - 128;
    int swz = (p & 7) * 132 + (p >> 3);     // bijective: 1056 = 8*132
    int b = swz / NBLK;
    int l = swz - b * NBLK;
    int rt = (int)((sqrtf(8.f * l + 1.f) - 1.f) * 0.5f);
    while ((rt + 1) * (rt + 2) / 2 <= l) ++rt;
    while (rt * (rt + 1) / 2 > l) --rt;
    int ct = l - rt * (rt + 1) / 2;
    int r0 = rt << 7, c0 = ct << 7;
    int base = b * T;

    int wr = (w >> 1) << 6, wc = (w & 1) << 6;
    bool active = !(rt == ct && w == 1);   // diag block, fully non-causal quadrant
    int fqs = (fq ^ ((fr >> 1) & 3)) << 3; // swizzled 16B-slot (bf16 offset)

    // staging: lane i of wave w covers (row 16w + (i>>2), swizzled 16B-chunk)
    int lrow = lane >> 2;
    int lcq = (((lane & 3) ^ ((lane >> 3) & 3)) << 3);   // pre-swizzled source slot
    const __bf16* gA = xhi + (size_t)(base + r0) * D;
    const __bf16* gB = xhi + (size_t)(base + c0) * D;
    const __bf16* gA0 = gA + (size_t)((w << 4) + lrow) * D + lcq;
    const __bf16* gA1 = gA0 + (size_t)64 * D;
    const __bf16* gB0 = gB + (size_t)((w << 4) + lrow) * D + lcq;
    const __bf16* gB1 = gB0 + (size_t)64 * D;

    f32x4 acc[4][4];
    #pragma unroll
    for (int i = 0; i < 4; ++i)
        #pragma unroll
        for (int j = 0; j < 4; ++j) acc[i][j] = (f32x4){0.f, 0.f, 0.f, 0.f};

#define ISSUE_A(BUFBASE, KO) do { \
    __bf16* bA_ = (BUFBASE); \
    __builtin_amdgcn_global_load_lds((const AS1 unsigned int*)(gA0 + (KO)), \
        (AS3 unsigned int*)(bA_ + (w << 9)), 16, 0, 0); \
    __builtin_amdgcn_global_load_lds((const AS1 unsigned int*)(gA1 + (KO)), \
        (AS3 unsigned int*)(bA_ + 2048 + (w << 9)), 16, 0, 0); \
} while (0)
#define ISSUE_B(BUFBASE, KO) do { \
    __bf16* bB_ = (BUFBASE); \
    __builtin_amdgcn_global_load_lds((const AS1 unsigned int*)(gB0 + (KO)), \
        (AS3 unsigned int*)(bB_ + (w << 9)), 16, 0, 0); \
    __builtin_amdgcn_global_load_lds((const AS1 unsigned int*)(gB1 + (KO)), \
        (AS3 unsigned int*)(bB_ + 2048 + (w << 9)), 16, 0, 0); \
} while (0)

    // prologue, ordinal [B(0), A(0), A(1)]
    ISSUE_B(stg + 12288, 0);
    ISSUE_A(stg, 0);
    ISSUE_A(stg + 4096, 32);

    int asel = 0, isel = 2;
    for (int kc = 0; kc < 32; ++kc) {
        // steady outstanding at wait: [A(k) 2, B(k) 2, A(k+1) 2] (oldest->newest)
        // vmcnt(2) drains A(k), B(k); A(k+1)'s 2 loads stay in flight.
        if (kc < 31) { asm volatile("s_waitcnt vmcnt(2)" ::: "memory"); }
        else         { asm volatile("s_waitcnt vmcnt(0)" ::: "memory"); }
        __builtin_amdgcn_s_barrier();      // buffers for tile kc visible
        asm volatile("" ::: "memory");
        if (kc + 1 < 32)                   // B(k+1) into bbuf[(k+1)&1] (read iter k-1)
            ISSUE_B(stg + 12288 + (((kc + 1) & 1) << 12), (kc + 1) << 5);
        if (kc + 2 < 32) {                 // A(k+2) into abuf[(k+2)%3] (read iter k-1)
            ISSUE_A(stg + (isel << 12), (kc + 2) << 5);
            isel = (isel == 2) ? 0 : isel + 1;
        }
        if (active) {
            const __bf16* cA = stg + (asel << 12);
            const __bf16* cB = stg + 12288 + ((kc & 1) << 12);
            bf16x8 ah[4], bh[4];
            #pragma unroll
            for (int i = 0; i < 4; ++i) {
                int ar = wr + i * 16 + fr;
                ah[i] = *(const bf16x8*)(cA + ar * 32 + fqs);
                int bc = wc + i * 16 + fr;
                bh[i] = *(const bf16x8*)(cB + bc * 32 + fqs);
            }
            #pragma unroll
            for (int i = 0; i < 4; ++i)
                #pragma unroll
                for (int j = 0; j < 4; ++j)
                    acc[i][j] = __builtin_amdgcn_mfma_f32_16x16x32_bf16(ah[i], bh[j], acc[i][j], 0, 0, 0);
        }
        asel = (asel == 2) ? 0 : asel + 1;
    }
#undef ISSUE_A
#undef ISSUE_B

    // ---- single-phase bf16 scan epilogue ----
    __syncthreads();                       // all MFMA ds_reads of staging done
    // write: wave w's quadrant rows wr+i*16+fq*4+r, cols wc+j*16+fr (bf16)
    {
        int cr = fq << 2;
        #pragma unroll
        for (int i = 0; i < 4; ++i) {
            int R0 = wr + i * 16 + cr;
            #pragma unroll
            for (int j = 0; j < 4; ++j) {
                int C = wc + j * 16 + fr;
                #pragma unroll
                for (int r = 0; r < 4; ++r)
                    Sb[(R0 + r) * 130 + C] = (__bf16)acc[i][j][r];
            }
        }
    }
    __syncthreads();
    // scan: wave w owns rows (w<<5)+(lane&31); half = lane>>5 covers 64 cols
    {
        int srow = (w << 5) + (lane & 31);
        int half = lane >> 5;
        int gt = r0 + srow;
        int cmax = gt - c0;
        if (cmax > 128) cmax = 128;
        if (cmax < 0) cmax = 0;
        int h0 = half << 6;
        int hmax = cmax < (h0 + 64) ? cmax : (h0 + 64);
        unsigned key[NK];
        #pragma unroll
        for (int i = 0; i < NK; ++i) key[i] = 0u;
        const __bf16* Srow = Sb + srow * 130;
        #pragma unroll
        for (int mb = 0; mb < 8; ++mb) {               // 8 batches of 8 cols
            int cb = h0 + (mb << 3);
            bf16x8 v8 = *(const bf16x8*)(Srow + cb);   // 16B, banks uniform
            #pragma unroll
            for (int j = 0; j < 8; ++j) {
                int c = cb + j;
                unsigned u = mono32((float)v8[j]);
                unsigned tk = (c < hmax) ? ((u & 0xFFFFFF80u) | (unsigned)(127 - c)) : 0u;
                #pragma unroll
                for (int i = 0; i < NK; ++i) {          // branchless sorted insert
                    unsigned hi = key[i] > tk ? key[i] : tk;
                    unsigned lo = key[i] > tk ? tk : key[i];
                    key[i] = hi; tk = lo;
                }
            }
        }
        // merge halves: one shfl_xor(32) + bitonic merge12
        {
            unsigned o12[NK], m12[NK];
            #pragma unroll
            for (int i = 0; i < NK; ++i) o12[i] = __shfl_xor(key[i], 32);
            merge12(key, o12, m12);
            #pragma unroll
            for (int i = 0; i < NK; ++i) key[i] = m12[i];
        }
        if (half == 0) {                   // store 12 keys as 3 dwordx4
            int ob = (base + gt) * CPR + ct * NK;
            #pragma unroll
            for (int part = 0; part < 3; ++part) {
                u32x4 ov;
                #pragma unroll
                for (int j = 0; j < 4; ++j) {
                    unsigned k0 = key[part * 4 + j];
                    // repack: value20 | (4095 - gcol), gcol = c0 + 127 - (k0&127)
                    ov[j] = k0 ? ((k0 & 0xFFFFF000u) | ((k0 & 127u) + (unsigned)(3968 - c0))) : 0u;
                }
                *(u32x4*)(pkey + ob + (part << 2)) = ov;
            }
        }
    }
}

// ---------------- K_C: FUSED wave-per-row selection + message + gelu ---------
// u32 packed-key candidates; 12 DPP extract-max passes (winners wave-uniform
// in SGPRs); scalar-addressed exact re-rank with DPP sum reduce; u64 exact
// top-8 insert; DPP 8-group score reduce. t==0 rows sum the 16 meansum2
// partials inline (2 waves in the whole grid).
__global__ __launch_bounds__(256) void select_msg_kernel(const float* __restrict__ x,
        const float* __restrict__ q, const float* __restrict__ k,
        const float* __restrict__ meansum2,
        const unsigned* __restrict__ pkey,
        const float* __restrict__ gain, const float* __restrict__ bias,
        const float* __restrict__ plm, const float* __restrict__ pls,
        float* __restrict__ out)
{
    int tid = threadIdx.x;
    int w = tid >> 6, lane = tid & 63;
    int rid = (blockIdx.x << 2) + w;         // global row b*T+t
    int b = rid >> 12, t = rid & (T - 1);
    int ncand = NK * ((t + 127) >> 7);

    // candidate loads (all in flight)
    unsigned cv[6];
    #pragma unroll
    for (int u = 0; u < 6; ++u) {
        int cid = lane + (u << 6);
        cv[u] = (cid < ncand) ? pkey[(size_t)rid * CPR + cid] : 0u;
    }
    // prefetch xt fragments (independent of merge)
    const float* xt = x + (size_t)rid * D;
    float4 xt4[4];
    #pragma unroll
    for (int c = 0; c < 4; ++c)
        xt4[c] = *(const float4*)(xt + (c << 8) + (lane << 2));

    // 12 DPP extract-max passes -> wave-uniform winners (keys unique: idx in key)
    unsigned skey[NK]; int sgid[NK];
    #pragma unroll
    for (int i = 0; i < NK; ++i) {
        unsigned m = cv[0];
        #pragma unroll
        for (int u = 1; u < 6; ++u) m = m > cv[u] ? m : cv[u];
        m = dpp_umax_bcast(m);               // uniform (SGPR)
        skey[i] = m;
        sgid[i] = 4095 - (int)(m & 4095u);
        #pragma unroll
        for (int u = 0; u < 6; ++u) cv[u] = (cv[u] == m) ? 0u : cv[u];
    }

    // exact fp32 re-rank: 3 batches of 4; uniform row bases, DPP sum reduce
    float ex[NK];
    #pragma unroll
    for (int batch = 0; batch < 3; ++batch) {
        float4 rv[4][4];
        #pragma unroll
        for (int s = 0; s < 4; ++s) {
            int i = batch * 4 + s;
            int row = (skey[i] != 0u) ? sgid[i] : 0;
            const float* xj = x + (size_t)((b << 12) + row) * D;
            #pragma unroll
            for (int c = 0; c < 4; ++c)
                rv[s][c] = *(const float4*)(xj + (c << 8) + (lane << 2));
        }
        #pragma unroll
        for (int s = 0; s < 4; ++s) {
            float ss = 0.f;
            #pragma unroll
            for (int c = 0; c < 4; ++c)
                ss += xt4[c].x * rv[s][c].x + xt4[c].y * rv[s][c].y
                    + xt4[c].z * rv[s][c].z + xt4[c].w * rv[s][c].w;
            ex[batch * 4 + s] = dpp_fsum_bcast(ss);   // uniform
        }
    }

    // exact top-8 via u64 packed keys: (mono(value) << 12) | (4095 - idx)
    unsigned long long top8[8];
    #pragma unroll
    for (int r = 0; r < 8; ++r) top8[r] = 0ull;
    #pragma unroll
    for (int i = 0; i < NK; ++i) {
        unsigned u = mono32(ex[i]);
        unsigned long long t64 = (skey[i] != 0u)
            ? ((((unsigned long long)u) << 12) | (unsigned long long)(4095 - sgid[i]))
            : 0ull;
        #pragma unroll
        for (int r = 0; r < 8; ++r) {       // branchless sorted insert
            unsigned long long hi = (t64 > top8[r]) ? t64 : top8[r];
            unsigned long long lo = (t64 > top8[r]) ? top8[r] : t64;
            top8[r] = hi; t64 = lo;
        }
    }
    bool vld[8]; int bidx[8];
    #pragma unroll
    for (int i = 0; i < 8; ++i) {
        vld[i]  = top8[i] != 0ull;
        bidx[i] = 4095 - (int)(top8[i] & 4095ull);
    }

    // scores: lanes 8i..8i+7 compute dot(q[t], k[sel_i]); key via cndmask tree
    int i8 = lane >> 3, e = lane & 7;
    unsigned long long kk = (i8 & 4)
        ? ((i8 & 2) ? ((i8 & 1) ? top8[7] : top8[6]) : ((i8 & 1) ? top8[5] : top8[4]))
        : ((i8 & 2) ? ((i8 & 1) ? top8[3] : top8[2]) : ((i8 & 1) ? top8[1] : top8[0]));
    bool v8 = kk != 0ull;
    int g8 = v8 ? (4095 - (int)(kk & 4095ull)) : 0;
    float4 qv = *(const float4*)(q + (size_t)rid * DH + (e << 2));
    float4 kv = *(const float4*)(k + (size_t)((b << 12) + g8) * DH + (e << 2));
    float p = qv.x * kv.x + qv.y * kv.y + qv.z * kv.z + qv.w * kv.w;
    p = dpp_gsum8(p);
    p *= 0.17677669529663687f;               // 1/sqrt(32)

    float sc[8];
    #pragma unroll
    for (int i = 0; i < 8; ++i)
        sc[i] = __int_as_float(__builtin_amdgcn_readlane(__float_as_int(p), i << 3));

    float m = -INFINITY; int cnt = 0;
    #pragma unroll
    for (int i = 0; i < 8; ++i)
        if (vld[i]) { ++cnt; if (sc[i] > m) m = sc[i]; }

    float wgt[8]; float Z = 0.f; int gsel[8];
    #pragma unroll
    for (int i = 0; i < 8; ++i) {
        wgt[i] = vld[i] ? expf(sc[i] - m) : 0.f;
        Z += wgt[i];
        gsel[i] = vld[i] ? ((b << 12) + bidx[i]) : (b << 12);
    }
    float invZ = (cnt > 0) ? 1.f / Z : 0.f;
    #pragma unroll
    for (int i = 0; i < 8; ++i) wgt[i] *= invZ;

    // ---- fused epilogue: msg accumulation on lane's 16 dims + gelu ----
    float mix   = 1.f / (1.f + expf(-plm[0]));
    float scale = log1pf(expf(pls[0])) + 0.01f;
    const float onemix = 1.f - mix;

    float4 msg4[4];
    if (cnt == 0) {                          // t==0: uniform attention over ALL T
        #pragma unroll
        for (int c = 0; c < 4; ++c) {
            int d0 = (c << 8) + (lane << 2);
            float4 a4 = (float4){0.f, 0.f, 0.f, 0.f};
            #pragma unroll
            for (int tch = 0; tch < 16; ++tch) {
                float4 ms = *(const float4*)(meansum2 + (((b << 4) + tch) << 10) + d0);
                a4.x += ms.x; a4.y += ms.y; a4.z += ms.z; a4.w += ms.w;
            }
            msg4[c].x = a4.x * (1.f / (float)T); msg4[c].y = a4.y * (1.f / (float)T);
            msg4[c].z = a4.z * (1.f / (float)T); msg4[c].w = a4.w * (1.f / (float)T);
        }
    } else {
        #pragma unroll
        for (int c = 0; c < 4; ++c) msg4[c] = (float4){0.f, 0.f, 0.f, 0.f};
        #pragma unroll
        for (int g = 0; g < 2; ++g) {        // 2 batches of 4 rows (L2-hot re-read)
            float4 rv[4][4];
            #pragma unroll
            for (int s = 0; s < 4; ++s) {
                const float* xj = x + (size_t)gsel[g * 4 + s] * D;
                #pragma unroll
                for (int c = 0; c < 4; ++c)
                    rv[s][c] = *(const float4*)(xj + (c << 8) + (lane << 2));
            }
            #pragma unroll
            for (int s = 0; s < 4; ++s) {    // preserves i=0..7 summation order
                float wi = wgt[g * 4 + s];
                #pragma unroll
                for (int c = 0; c < 4; ++c) {
                    msg4[c].x += wi * rv[s][c].x; msg4[c].y += wi * rv[s][c].y;
                    msg4[c].z += wi * rv[s][c].z; msg4[c].w += wi * rv[s][c].w;
                }
            }
        }
    }
    #pragma unroll
    for (int c = 0; c < 4; ++c) {
        int d0 = (c << 8) + (lane << 2);
        float4 g4 = *(const float4*)(gain + d0);
        float4 b4 = *(const float4*)(bias + d0);
        float4 xv = xt4[c];
        float zi[4] = {
            (mix * xv.x + onemix * msg4[c].x) * g4.x + b4.x,
            (mix * xv.y + onemix * msg4[c].y) * g4.y + b4.y,
            (mix * xv.z + onemix * msg4[c].z) * g4.z + b4.z,
            (mix * xv.w + onemix * msg4[c].w) * g4.w + b4.w };
        float4 o4;
        o4.x = 0.5f * zi[0] * (1.f + erff(zi[0] * 0.70710678118654752f)) * scale;
        o4.y = 0.5f * zi[1] * (1.f + erff(zi[1] * 0.70710678118654752f)) * scale;
        o4.z = 0.5f * zi[2] * (1.f + erff(zi[2] * 0.70710678118654752f)) * scale;
        o4.w = 0.5f * zi[3] * (1.f + erff(zi[3] * 0.70710678118654752f)) * scale;
        *(float4*)(out + (size_t)rid * D + d0) = o4;
    }
}

extern "C" void kernel_launch(void* const* d_in, const int* in_sizes, int n_in,
                              void* d_out, int out_size, void* d_ws, size_t ws_size,
                              hipStream_t stream)
{
    const float* x    = (const float*)d_in[0];
    const float* Wq   = (const float*)d_in[1];
    const float* Wk   = (const float*)d_in[2];
    const float* gain = (const float*)d_in[3];
    const float* bias = (const float*)d_in[4];
    const float* plm  = (const float*)d_in[5];
    const float* pls  = (const float*)d_in[6];
    float* out = (float*)d_out;

    float* ws       = (float*)d_ws;
    float* q        = ws;                        // 262144
    float* k        = ws + 262144;               // 262144
    float* meansum2 = ws + 524288;               // B*16*1024 = 32768
    unsigned* pkey  = (unsigned*)(ws + 557056);  // B*T*CPR u32 = 3145728 slots
    __bf16* xhi     = (__bf16*)(ws + 3702784);   // B*T*D bf16
    __bf16* xlo     = xhi + (size_t)B * T * D;
    __bf16* Whi     = xlo + (size_t)B * T * D;   // 64*1024 bf16
    __bf16* Wlo     = Whi + 64 * D;
    // total ws use: ~49 MB

    prep_kernel<<<4256, 256, 0, stream>>>(x, Wq, Wk, xhi, xlo, Whi, Wlo, meansum2);
    qk_topk_kernel<<<128 + B * NBLK, 256, 0, stream>>>(xhi, xlo, Whi, Wlo, q, k, pkey);
    select_msg_kernel<<<B * T / 4, 256, 0, stream>>>(x, q, k, meansum2, pkey,
                                                     gain, bias, plm, pls, out);
}

// Round 10
// 225.316 us; speedup vs baseline: 1.3141x; 1.0251x over previous
//
#include <hip/hip_runtime.h>
#include <math.h>

#define B 2
#define T 4096
#define D 1024
#define DH 32
#define TNB 32        // 128-row tiles per batch
#define NBLK 528      // TNB*(TNB+1)/2 causal tile pairs
#define NK 12         // per-chunk candidates kept (safety margin over 8)
#define CPR (32*NK)   // candidates per row = 384

typedef __bf16 bf16x8 __attribute__((ext_vector_type(8)));
typedef float f32x4 __attribute__((ext_vector_type(4)));
typedef unsigned u32x4 __attribute__((ext_vector_type(4)));

#define AS1 __attribute__((address_space(1)))
#define AS3 __attribute__((address_space(3)))

// monotone f32 -> u32 (order-preserving); branchless
__device__ __forceinline__ unsigned mono32(float v) {
    unsigned u = __float_as_uint(v);
    u ^= ((unsigned)((int)u >> 31)) | 0x80000000u;
    return u;
}

// ---- wave-wide u32 max, result broadcast via readlane(63) (uniform/SGPR) ----
__device__ __forceinline__ unsigned dpp_umax_bcast(unsigned v) {
    #define DPPMAX(CTRL) { unsigned t_ = (unsigned)__builtin_amdgcn_update_dpp(0, (int)v, CTRL, 0xF, 0xF, true); v = v > t_ ? v : t_; }
    DPPMAX(0x111) DPPMAX(0x112) DPPMAX(0x114) DPPMAX(0x118)   // row_shr 1,2,4,8
    DPPMAX(0x142) DPPMAX(0x143)                               // row_bcast 15,31
    #undef DPPMAX
    return (unsigned)__builtin_amdgcn_readlane((int)v, 63);
}
// ---- wave-wide f32 sum, result broadcast via readlane(63) (uniform/SGPR) ----
__device__ __forceinline__ float dpp_fsum_bcast(float v) {
    #define DPPADD(CTRL) { int t_ = __builtin_amdgcn_update_dpp(0, __float_as_int(v), CTRL, 0xF, 0xF, true); v += __int_as_float(t_); }
    DPPADD(0x111) DPPADD(0x112) DPPADD(0x114) DPPADD(0x118)
    DPPADD(0x142) DPPADD(0x143)
    #undef DPPADD
    return __int_as_float(__builtin_amdgcn_readlane(__float_as_int(v), 63));
}
// ---- sum across each aligned 8-lane group (all lanes get the sum) ----
__device__ __forceinline__ float dpp_gsum8(float p) {
    { int t_ = __builtin_amdgcn_update_dpp(0, __float_as_int(p), 0x0B1, 0xF, 0xF, true); p += __int_as_float(t_); } // quad_perm xor1
    { int t_ = __builtin_amdgcn_update_dpp(0, __float_as_int(p), 0x04E, 0xF, 0xF, true); p += __int_as_float(t_); } // quad_perm xor2
    { int t_ = __builtin_amdgcn_update_dpp(0, __float_as_int(p), 0x141, 0xF, 0xF, true); p += __int_as_float(t_); } // row_half_mirror (xor7)
    return p;
}

// ---- bitonic merge of two sorted-desc 12-lists (packed unique keys) ----
__device__ __forceinline__ void merge12(const unsigned* a12, const unsigned* b12,
                                        unsigned* o12) {
    unsigned m16[16];
    #pragma unroll
    for (int i = 0; i < 16; ++i) {          // bitonic split, keep top-16
        unsigned aa = (i < NK) ? a12[i] : 0u;
        unsigned bb = (15 - i < NK) ? b12[15 - i] : 0u;
        m16[i] = aa > bb ? aa : bb;
    }
    #pragma unroll
    for (int g = 8; g >= 1; g >>= 1) {      // bitonic merge, descending
        #pragma unroll
        for (int i = 0; i < 16; ++i) {
            if (!(i & g)) {
                unsigned x0 = m16[i], x1 = m16[i + g];
                m16[i]     = x0 > x1 ? x0 : x1;
                m16[i + g] = x0 > x1 ? x1 : x0;
            }
        }
    }
    #pragma unroll
    for (int i = 0; i < NK; ++i) o12[i] = m16[i];
}

// ---- shared conv body: 2048 consecutive floats -> (hi,lo) bf16 -------------
__device__ __forceinline__ void conv_body(const float* __restrict__ src,
        __bf16* __restrict__ dhi, __bf16* __restrict__ dlo, int i)
{
    float4 a = *(const float4*)(src + i);
    float4 c = *(const float4*)(src + i + 4);
    float av[8] = {a.x, a.y, a.z, a.w, c.x, c.y, c.z, c.w};
    __bf16 h[8], l[8];
    #pragma unroll
    for (int j = 0; j < 8; ++j) {
        h[j] = (__bf16)av[j];
        l[j] = (__bf16)(av[j] - (float)h[j]);
    }
    *(float4*)(dhi + i) = *(float4*)h;
    *(float4*)(dlo + i) = *(float4*)l;
}

// ---------------- K_A: FUSED partial-mean + convX + convW (one launch) -------
// blocks [0,512): per-(b,tch,dblk) 64-row column partial sums -> meansum2
//   (FIRST in grid so they overlap conv instead of forming a tail; no
//   atomics, no memset: each block owns a private slot);
// blocks [512,4608): x -> (xhi,xlo); [4608,4640): Wq/Wk -> (Whi,Wlo).
__global__ __launch_bounds__(256) void prep_kernel(const float* __restrict__ x,
        const float* __restrict__ Wq, const float* __restrict__ Wk,
        __bf16* __restrict__ xhi, __bf16* __restrict__ xlo,
        __bf16* __restrict__ Whi, __bf16* __restrict__ Wlo,
        float* __restrict__ meansum2)
{
    int g = blockIdx.x;
    if (g < 512) {                       // B * 4 dblk * 64 tch = 512 blocks
        int b = g >> 8;
        int rem = g & 255;
        int dblk = rem >> 6;
        int tch = rem & 63;
        int d = dblk * 256 + threadIdx.x;
        const float* xp = x + (b * T + tch * 64) * D + d;
        float s = 0.f;
        #pragma unroll 8
        for (int it = 0; it < 64; ++it) s += xp[it * D];
        meansum2[(((b << 6) + tch) << 10) + d] = s;   // private slot, plain store
    } else if (g < 4608) {
        int gx = g - 512;
        conv_body(x, xhi, xlo, (gx * 256 + threadIdx.x) << 3);
    } else {
        int gw = g - 4608;
        const float* src = (gw < 16) ? Wq : Wk;
        __bf16* dhi = Whi + ((gw < 16) ? 0 : 32 * D);
        __bf16* dlo = Wlo + ((gw < 16) ? 0 : 32 * D);
        conv_body(src, dhi, dlo, ((gw & 15) * 256 + threadIdx.x) << 3);
    }
}

// ---------------- K_B: FUSED qk projection + topk sim GEMM (one launch) ------
// blocks [0,128): qk (split-bf16 MFMA, 64-row blocks, 20KB of smem);
// blocks [128,1184): topk with bijective XCD swizzle (1056 = 8*132).
// topk K-loop = r7/r8 verified structure: A triple-buffered + B double-
// buffered (40960 B, 4 blk/CU), counted vmcnt(2), ONE barrier/iter.
// Epilogue: SINGLE-phase bf16 Sbuf [128][132] (33792 B; stride 264 B = bank
// shift 2 per row -> write/read conflicts <=4-way): one write pass, one scan
// pass. Per-lane 64-col half-scan + 1x shfl_xor(32)+merge12; half-0 lane
// stores 12 keys (3x dwordx4). Output: value[31:12] | (4095 - gidx).
__global__ __launch_bounds__(256, 4) void qk_topk_kernel(
        const __bf16* __restrict__ xhi, const __bf16* __restrict__ xlo,
        const __bf16* __restrict__ Whi, const __bf16* __restrict__ Wlo,
        float* __restrict__ qo, float* __restrict__ ko,
        unsigned* __restrict__ pkey)
{
    __shared__ __align__(16) char smem[40960];
    int tid = threadIdx.x;
    int w = tid >> 6, lane = tid & 63;
    int fr = lane & 15, fq = lane >> 4;

    if (blockIdx.x < 128) {
        // ---------------- qk body (r8 verbatim) ----------------
        __bf16* sAhi = (__bf16*)smem;          // 64 x 40
        __bf16* sAlo = sAhi + 2560;
        __bf16* sBhi = sAhi + 5120;            // 64 x 40
        __bf16* sBlo = sAhi + 7680;

        int m0 = blockIdx.x << 6;
        int arow = tid >> 2, aq = tid & 3;     // 4 chunks of 8 bf16 per row
        const __bf16* gAh = xhi + (size_t)(m0 + arow) * D + aq * 8;
        const __bf16* gAl = xlo + (size_t)(m0 + arow) * D + aq * 8;
        const __bf16* gBh = Whi + arow * D + aq * 8;
        const __bf16* gBl = Wlo + arow * D + aq * 8;

        f32x4 acc[4];
        #pragma unroll
        for (int j = 0; j < 4; ++j) acc[j] = (f32x4){0.f, 0.f, 0.f, 0.f};

        float4 a0 = *(const float4*)(gAh);
        float4 a1 = *(const float4*)(gAl);
        float4 b0 = *(const float4*)(gBh);
        float4 b1 = *(const float4*)(gBl);

        int sa = arow * 40 + aq * 8;

        for (int kc = 0; kc < 32; ++kc) {
            __syncthreads();
            *(float4*)(sAhi + sa) = a0;
            *(float4*)(sAlo + sa) = a1;
            *(float4*)(sBhi + sa) = b0;
            *(float4*)(sBlo + sa) = b1;
            __syncthreads();
            if (kc + 1 < 32) {
                int k0 = (kc + 1) << 5;
                a0 = *(const float4*)(gAh + k0);
                a1 = *(const float4*)(gAl + k0);
                b0 = *(const float4*)(gBh + k0);
                b1 = *(const float4*)(gBl + k0);
            }
            int r = (w << 4) + fr;
            bf16x8 fah = *(const bf16x8*)(sAhi + r * 40 + fq * 8);
            bf16x8 fal = *(const bf16x8*)(sAlo + r * 40 + fq * 8);
            bf16x8 fbh[4], fbl[4];
            #pragma unroll
            for (int j = 0; j < 4; ++j) {
                int rb = j * 16 + fr;
                fbh[j] = *(const bf16x8*)(sBhi + rb * 40 + fq * 8);
                fbl[j] = *(const bf16x8*)(sBlo + rb * 40 + fq * 8);
            }
            #pragma unroll
            for (int j = 0; j < 4; ++j) {
                acc[j] = __builtin_amdgcn_mfma_f32_16x16x32_bf16(fah, fbh[j], acc[j], 0, 0, 0);
                acc[j] = __builtin_amdgcn_mfma_f32_16x16x32_bf16(fah, fbl[j], acc[j], 0, 0, 0);
                acc[j] = __builtin_amdgcn_mfma_f32_16x16x32_bf16(fal, fbh[j], acc[j], 0, 0, 0);
            }
        }
        // writeout: C layout col=lane&15, row=fq*4+reg
        int grow0 = m0 + (w << 4) + (fq << 2);
        #pragma unroll
        for (int j = 0; j < 4; ++j) {
            int gn = j * 16 + fr;
            float* dst = (gn < 32) ? (qo + grow0 * DH + gn)
                                   : (ko + grow0 * DH + gn - 32);
            dst[0]      = acc[j][0];
            dst[DH]     = acc[j][1];
            dst[2 * DH] = acc[j][2];
            dst[3 * DH] = acc[j][3];
        }
        return;
    }

    // ---------------- topk body ----------------
    __bf16* stg = (__bf16*)smem;   // A bufs @ 0,4096,8192; B bufs @ 12288,16384
    __bf16* Sb  = (__bf16*)smem;   // post-loop: bf16 [128][132] = 33792 B

    int p = blockIdx.x - 128;
    int swz = (p & 7) * 132 + (p >> 3);     // bijective: 1056 = 8*132
    int b = swz / NBLK;
    int l = swz - b * NBLK;
    int rt = (int)((sqrtf(8.f * l + 1.f) - 1.f) * 0.5f);
    while ((rt + 1) * (rt + 2) / 2 <= l) ++rt;
    while (rt * (rt + 1) / 2 > l) --rt;
    int ct = l - rt * (rt + 1) / 2;
    int r0 = rt << 7, c0 = ct << 7;
    int base = b * T;

    int wr = (w >> 1) << 6, wc = (w & 1) << 6;
    bool active = !(rt == ct && w == 1);   // diag block, fully non-causal quadrant
    int fqs = (fq ^ ((fr >> 1) & 3)) << 3; // swizzled 16B-slot (bf16 offset)

    // staging: lane i of wave w covers (row 16w + (i>>2), swizzled 16B-chunk)
    int lrow = lane >> 2;
    int lcq = (((lane & 3) ^ ((lane >> 3) & 3)) << 3);   // pre-swizzled source slot
    const __bf16* gA = xhi + (size_t)(base + r0) * D;
    const __bf16* gB = xhi + (size_t)(base + c0) * D;
    const __bf16* gA0 = gA + (size_t)((w << 4) + lrow) * D + lcq;
    const __bf16* gA1 = gA0 + (size_t)64 * D;
    const __bf16* gB0 = gB + (size_t)((w << 4) + lrow) * D + lcq;
    const __bf16* gB1 = gB0 + (size_t)64 * D;

    f32x4 acc[4][4];
    #pragma unroll
    for (int i = 0; i < 4; ++i)
        #pragma unroll
        for (int j = 0; j < 4; ++j) acc[i][j] = (f32x4){0.f, 0.f, 0.f, 0.f};

#define ISSUE_A(BUFBASE, KO) do { \
    __bf16* bA_ = (BUFBASE); \
    __builtin_amdgcn_global_load_lds((const AS1 unsigned int*)(gA0 + (KO)), \
        (AS3 unsigned int*)(bA_ + (w << 9)), 16, 0, 0); \
    __builtin_amdgcn_global_load_lds((const AS1 unsigned int*)(gA1 + (KO)), \
        (AS3 unsigned int*)(bA_ + 2048 + (w << 9)), 16, 0, 0); \
} while (0)
#define ISSUE_B(BUFBASE, KO) do { \
    __bf16* bB_ = (BUFBASE); \
    __builtin_amdgcn_global_load_lds((const AS1 unsigned int*)(gB0 + (KO)), \
        (AS3 unsigned int*)(bB_ + (w << 9)), 16, 0, 0); \
    __builtin_amdgcn_global_load_lds((const AS1 unsigned int*)(gB1 + (KO)), \
        (AS3 unsigned int*)(bB_ + 2048 + (w << 9)), 16, 0, 0); \
} while (0)

    // prologue, ordinal [B(0), A(0), A(1)]
    ISSUE_B(stg + 12288, 0);
    ISSUE_A(stg, 0);
    ISSUE_A(stg + 4096, 32);

    int asel = 0, isel = 2;
    for (int kc = 0; kc < 32; ++kc) {
        // steady outstanding at wait: [A(k) 2, B(k) 2, A(k+1) 2] (oldest->newest)
        // vmcnt(2) drains A(k), B(k); A(k+1)'s 2 loads stay in flight.
        if (kc < 31) { asm volatile("s_waitcnt vmcnt(2)" ::: "memory"); }
        else         { asm volatile("s_waitcnt vmcnt(0)" ::: "memory"); }
        __builtin_amdgcn_s_barrier();      // buffers for tile kc visible
        asm volatile("" ::: "memory");
        if (kc + 1 < 32)                   // B(k+1) into bbuf[(k+1)&1] (read iter k-1)
            ISSUE_B(stg + 12288 + (((kc + 1) & 1) << 12), (kc + 1) << 5);
        if (kc + 2 < 32) {                 // A(k+2) into abuf[(k+2)%3] (read iter k-1)
            ISSUE_A(stg + (isel << 12), (kc + 2) << 5);
            isel = (isel == 2) ? 0 : isel + 1;
        }
        if (active) {
            const __bf16* cA = stg + (asel << 12);
            const __bf16* cB = stg + 12288 + ((kc & 1) << 12);
            bf16x8 ah[4], bh[4];
            #pragma unroll
            for (int i = 0; i < 4; ++i) {
                int ar = wr + i * 16 + fr;
                ah[i] = *(const bf16x8*)(cA + ar * 32 + fqs);
                int bc = wc + i * 16 + fr;
                bh[i] = *(const bf16x8*)(cB + bc * 32 + fqs);
            }
            #pragma unroll
            for (int i = 0; i < 4; ++i)
                #pragma unroll
                for (int j = 0; j < 4; ++j)
                    acc[i][j] = __builtin_amdgcn_mfma_f32_16x16x32_bf16(ah[i], bh[j], acc[i][j], 0, 0, 0);
        }
        asel = (asel == 2) ? 0 : asel + 1;
    }
#undef ISSUE_A
#undef ISSUE_B

    // ---- single-phase bf16 scan epilogue ----
    __syncthreads();                       // all MFMA ds_reads of staging done
    // write: wave w's quadrant rows wr+i*16+fq*4+r, cols wc+j*16+fr (bf16)
    {
        int cr = fq << 2;
        #pragma unroll
        for (int i = 0; i < 4; ++i) {
            int R0 = wr + i * 16 + cr;
            #pragma unroll
            for (int j = 0; j < 4; ++j) {
                int C = wc + j * 16 + fr;
                #pragma unroll
                for (int r = 0; r < 4; ++r)
                    Sb[(R0 + r) * 132 + C] = (__bf16)acc[i][j][r];
            }
        }
    }
    __syncthreads();
    // scan: wave w owns rows (w<<5)+(lane&31); half = lane>>5 covers 64 cols
    {
        int srow = (w << 5) + (lane & 31);
        int half = lane >> 5;
        int gt = r0 + srow;
        int cmax = gt - c0;
        if (cmax > 128) cmax = 128;
        if (cmax < 0) cmax = 0;
        int h0 = half << 6;
        int hmax = cmax < (h0 + 64) ? cmax : (h0 + 64);
        unsigned key[NK];
        #pragma unroll
        for (int i = 0; i < NK; ++i) key[i] = 0u;
        const __bf16* Srow = Sb + srow * 132;
        #pragma unroll
        for (int mb = 0; mb < 8; ++mb) {               // 8 batches of 8 cols
            int cb = h0 + (mb << 3);
            bf16x8 v8 = *(const bf16x8*)(Srow + cb);   // 16B chunk
            #pragma unroll
            for (int j = 0; j < 8; ++j) {
                int c = cb + j;
                unsigned u = mono32((float)v8[j]);
                unsigned tk = (c < hmax) ? ((u & 0xFFFFFF80u) | (unsigned)(127 - c)) : 0u;
                #pragma unroll
                for (int i = 0; i < NK; ++i) {          // branchless sorted insert
                    unsigned hi = key[i] > tk ? key[i] : tk;
                    unsigned lo = key[i] > tk ? tk : key[i];
                    key[i] = hi; tk = lo;
                }
            }
        }
        // merge halves: one shfl_xor(32) + bitonic merge12
        {
            unsigned o12[NK], m12[NK];
            #pragma unroll
            for (int i = 0; i < NK; ++i) o12[i] = __shfl_xor(key[i], 32);
            merge12(key, o12, m12);
            #pragma unroll
            for (int i = 0; i < NK; ++i) key[i] = m12[i];
        }
        if (half == 0) {                   // store 12 keys as 3 dwordx4
            int ob = (base + gt) * CPR + ct * NK;
            #pragma unroll
            for (int part = 0; part < 3; ++part) {
                u32x4 ov;
                #pragma unroll
                for (int j = 0; j < 4; ++j) {
                    unsigned k0 = key[part * 4 + j];
                    // repack: value20 | (4095 - gcol), gcol = c0 + 127 - (k0&127)
                    ov[j] = k0 ? ((k0 & 0xFFFFF000u) | ((k0 & 127u) + (unsigned)(3968 - c0))) : 0u;
                }
                *(u32x4*)(pkey + ob + (part << 2)) = ov;
            }
        }
    }
}

// ---------------- K_C: FUSED wave-per-row selection + message + gelu ---------
// u32 packed-key candidates; 12 DPP extract-max passes (winners wave-uniform
// in SGPRs); scalar-addressed exact re-rank with DPP sum reduce; u64 exact
// top-8 insert; DPP 8-group score reduce. t==0 rows sum the 64 meansum2
// partials inline (2 waves in the whole grid).
__global__ __launch_bounds__(256) void select_msg_kernel(const float* __restrict__ x,
        const float* __restrict__ q, const float* __restrict__ k,
        const float* __restrict__ meansum2,
        const unsigned* __restrict__ pkey,
        const float* __restrict__ gain, const float* __restrict__ bias,
        const float* __restrict__ plm, const float* __restrict__ pls,
        float* __restrict__ out)
{
    int tid = threadIdx.x;
    int w = tid >> 6, lane = tid & 63;
    int rid = (blockIdx.x << 2) + w;         // global row b*T+t
    int b = rid >> 12, t = rid & (T - 1);
    int ncand = NK * ((t + 127) >> 7);

    // candidate loads (all in flight)
    unsigned cv[6];
    #pragma unroll
    for (int u = 0; u < 6; ++u) {
        int cid = lane + (u << 6);
        cv[u] = (cid < ncand) ? pkey[(size_t)rid * CPR + cid] : 0u;
    }
    // prefetch xt fragments (independent of merge)
    const float* xt = x + (size_t)rid * D;
    float4 xt4[4];
    #pragma unroll
    for (int c = 0; c < 4; ++c)
        xt4[c] = *(const float4*)(xt + (c << 8) + (lane << 2));

    // 12 DPP extract-max passes -> wave-uniform winners (keys unique: idx in key)
    unsigned skey[NK]; int sgid[NK];
    #pragma unroll
    for (int i = 0; i < NK; ++i) {
        unsigned m = cv[0];
        #pragma unroll
        for (int u = 1; u < 6; ++u) m = m > cv[u] ? m : cv[u];
        m = dpp_umax_bcast(m);               // uniform (SGPR)
        skey[i] = m;
        sgid[i] = 4095 - (int)(m & 4095u);
        #pragma unroll
        for (int u = 0; u < 6; ++u) cv[u] = (cv[u] == m) ? 0u : cv[u];
    }

    // exact fp32 re-rank: 3 batches of 4; uniform row bases, DPP sum reduce
    float ex[NK];
    #pragma unroll
    for (int batch = 0; batch < 3; ++batch) {
        float4 rv[4][4];
        #pragma unroll
        for (int s = 0; s < 4; ++s) {
            int i = batch * 4 + s;
            int row = (skey[i] != 0u) ? sgid[i] : 0;
            const float* xj = x + (size_t)((b << 12) + row) * D;
            #pragma unroll
            for (int c = 0; c < 4; ++c)
                rv[s][c] = *(const float4*)(xj + (c << 8) + (lane << 2));
        }
        #pragma unroll
        for (int s = 0; s < 4; ++s) {
            float ss = 0.f;
            #pragma unroll
            for (int c = 0; c < 4; ++c)
                ss += xt4[c].x * rv[s][c].x + xt4[c].y * rv[s][c].y
                    + xt4[c].z * rv[s][c].z + xt4[c].w * rv[s][c].w;
            ex[batch * 4 + s] = dpp_fsum_bcast(ss);   // uniform
        }
    }

    // exact top-8 via u64 packed keys: (mono(value) << 12) | (4095 - idx)
    unsigned long long top8[8];
    #pragma unroll
    for (int r = 0; r < 8; ++r) top8[r] = 0ull;
    #pragma unroll
    for (int i = 0; i < NK; ++i) {
        unsigned u = mono32(ex[i]);
        unsigned long long t64 = (skey[i] != 0u)
            ? ((((unsigned long long)u) << 12) | (unsigned long long)(4095 - sgid[i]))
            : 0ull;
        #pragma unroll
        for (int r = 0; r < 8; ++r) {       // branchless sorted insert
            unsigned long long hi = (t64 > top8[r]) ? t64 : top8[r];
            unsigned long long lo = (t64 > top8[r]) ? top8[r] : t64;
            top8[r] = hi; t64 = lo;
        }
    }
    bool vld[8]; int bidx[8];
    #pragma unroll
    for (int i = 0; i < 8; ++i) {
        vld[i]  = top8[i] != 0ull;
        bidx[i] = 4095 - (int)(top8[i] & 4095ull);
    }

    // scores: lanes 8i..8i+7 compute dot(q[t], k[sel_i]); key via cndmask tree
    int i8 = lane >> 3, e = lane & 7;
    unsigned long long kk = (i8 & 4)
        ? ((i8 & 2) ? ((i8 & 1) ? top8[7] : top8[6]) : ((i8 & 1) ? top8[5] : top8[4]))
        : ((i8 & 2) ? ((i8 & 1) ? top8[3] : top8[2]) : ((i8 & 1) ? top8[1] : top8[0]));
    bool v8 = kk != 0ull;
    int g8 = v8 ? (4095 - (int)(kk & 4095ull)) : 0;
    float4 qv = *(const float4*)(q + (size_t)rid * DH + (e << 2));
    float4 kv = *(const float4*)(k + (size_t)((b << 12) + g8) * DH + (e << 2));
    float p = qv.x * kv.x + qv.y * kv.y + qv.z * kv.z + qv.w * kv.w;
    p = dpp_gsum8(p);
    p *= 0.17677669529663687f;               // 1/sqrt(32)

    float sc[8];
    #pragma unroll
    for (int i = 0; i < 8; ++i)
        sc[i] = __int_as_float(__builtin_amdgcn_readlane(__float_as_int(p), i << 3));

    float m = -INFINITY; int cnt = 0;
    #pragma unroll
    for (int i = 0; i < 8; ++i)
        if (vld[i]) { ++cnt; if (sc[i] > m) m = sc[i]; }

    float wgt[8]; float Z = 0.f; int gsel[8];
    #pragma unroll
    for (int i = 0; i < 8; ++i) {
        wgt[i] = vld[i] ? expf(sc[i] - m) : 0.f;
        Z += wgt[i];
        gsel[i] = vld[i] ? ((b << 12) + bidx[i]) : (b << 12);
    }
    float invZ = (cnt > 0) ? 1.f / Z : 0.f;
    #pragma unroll
    for (int i = 0; i < 8; ++i) wgt[i] *= invZ;

    // ---- fused epilogue: msg accumulation on lane's 16 dims + gelu ----
    float mix   = 1.f / (1.f + expf(-plm[0]));
    float scale = log1pf(expf(pls[0])) + 0.01f;
    const float onemix = 1.f - mix;

    float4 msg4[4];
    if (cnt == 0) {                          // t==0: uniform attention over ALL T
        #pragma unroll
        for (int c = 0; c < 4; ++c) {
            int d0 = (c << 8) + (lane << 2);
            float4 a4 = (float4){0.f, 0.f, 0.f, 0.f};
            for (int tch = 0; tch < 64; ++tch) {
                float4 ms = *(const float4*)(meansum2 + (((b << 6) + tch) << 10) + d0);
                a4.x += ms.x; a4.y += ms.y; a4.z += ms.z; a4.w += ms.w;
            }
            msg4[c].x = a4.x * (1.f / (float)T); msg4[c].y = a4.y * (1.f / (float)T);
            msg4[c].z = a4.z * (1.f / (float)T); msg4[c].w = a4.w * (1.f / (float)T);
        }
    } else {
        #pragma unroll
        for (int c = 0; c < 4; ++c) msg4[c] = (float4){0.f, 0.f, 0.f, 0.f};
        #pragma unroll
        for (int g = 0; g < 2; ++g) {        // 2 batches of 4 rows (L2-hot re-read)
            float4 rv[4][4];
            #pragma unroll
            for (int s = 0; s < 4; ++s) {
                const float* xj = x + (size_t)gsel[g * 4 + s] * D;
                #pragma unroll
                for (int c = 0; c < 4; ++c)
                    rv[s][c] = *(const float4*)(xj + (c << 8) + (lane << 2));
            }
            #pragma unroll
            for (int s = 0; s < 4; ++s) {    // preserves i=0..7 summation order
                float wi = wgt[g * 4 + s];
                #pragma unroll
                for (int c = 0; c < 4; ++c) {
                    msg4[c].x += wi * rv[s][c].x; msg4[c].y += wi * rv[s][c].y;
                    msg4[c].z += wi * rv[s][c].z; msg4[c].w += wi * rv[s][c].w;
                }
            }
        }
    }
    #pragma unroll
    for (int c = 0; c < 4; ++c) {
        int d0 = (c << 8) + (lane << 2);
        float4 g4 = *(const float4*)(gain + d0);
        float4 b4 = *(const float4*)(bias + d0);
        float4 xv = xt4[c];
        float zi[4] = {
            (mix * xv.x + onemix * msg4[c].x) * g4.x + b4.x,
            (mix * xv.y + onemix * msg4[c].y) * g4.y + b4.y,
            (mix * xv.z + onemix * msg4[c].z) * g4.z + b4.z,
            (mix * xv.w + onemix * msg4[c].w) * g4.w + b4.w };
        float4 o4;
        o4.x = 0.5f * zi[0] * (1.f + erff(zi[0] * 0.70710678118654752f)) * scale;
        o4.y = 0.5f * zi[1] * (1.f + erff(zi[1] * 0.70710678118654752f)) * scale;
        o4.z = 0.5f * zi[2] * (1.f + erff(zi[2] * 0.70710678118654752f)) * scale;
        o4.w = 0.5f * zi[3] * (1.f + erff(zi[3] * 0.70710678118654752f)) * scale;
        *(float4*)(out + (size_t)rid * D + d0) = o4;
    }
}

extern "C" void kernel_launch(void* const* d_in, const int* in_sizes, int n_in,
                              void* d_out, int out_size, void* d_ws, size_t ws_size,
                              hipStream_t stream)
{
    const float* x    = (const float*)d_in[0];
    const float* Wq   = (const float*)d_in[1];
    const float* Wk   = (const float*)d_in[2];
    const float* gain = (const float*)d_in[3];
    const float* bias = (const float*)d_in[4];
    const float* plm  = (const float*)d_in[5];
    const float* pls  = (const float*)d_in[6];
    float* out = (float*)d_out;

    float* ws       = (float*)d_ws;
    float* q        = ws;                        // 262144
    float* k        = ws + 262144;               // 262144
    float* meansum2 = ws + 524288;               // B*64*1024 = 131072
    unsigned* pkey  = (unsigned*)(ws + 655360);  // B*T*CPR u32 = 3145728 slots
    __bf16* xhi     = (__bf16*)(ws + 3801088);   // B*T*D bf16
    __bf16* xlo     = xhi + (size_t)B * T * D;
    __bf16* Whi     = xlo + (size_t)B * T * D;   // 64*1024 bf16
    __bf16* Wlo     = Whi + 64 * D;
    // total ws use: ~49 MB

    prep_kernel<<<4640, 256, 0, stream>>>(x, Wq, Wk, xhi, xlo, Whi, Wlo, meansum2);
    qk_topk_kernel<<<128 + B * NBLK, 256, 0, stream>>>(xhi, xlo, Whi, Wlo, q, k, pkey);
    select_msg_kernel<<<B * T / 4, 256, 0, stream>>>(x, q, k, meansum2, pkey,
                                                     gain, bias, plm, pls, out);
}